// Round 4
// baseline (1114.311 us; speedup 1.0000x reference)
//
#include <hip/hip_runtime.h>
#include <cstdint>
#include <cstddef>

// ---------------------------------------------------------------------------
// GCN 2-layer: out = GCNConv2( relu( GCNConv1(x) ) )
// Pipeline:
//   k_hist  : per-node in-degree histogram (for dinv AND bucket offsets)
//   k_dinv  : dinv = rsqrt(deg+1)
//   scan    : exclusive scan of cnt -> rowptr  (bucket b edges = rowptr[b*32]..)
//   k_binit : per-bucket append cursors = rowptr[b*32]
//   k_fill2 : append 4B packed records (dlocal<<25 | src) at bucket cursor
//             -> only 3125 active cursors => L2-resident write-combining
//   k_gemm  : H = X @ W   (LDS-staged W, 1 float4/thread, no spills)
//   k_push  : one block per bucket; LDS accumulator [32 nodes][C]; waves
//             stream bucket's edges, gather H[src] rows, atomicAdd into LDS;
//             epilogue adds self-loop + bias (+ReLU), coalesced store.
// Edge dtype (int32 vs int64) detected on-device via high words.
// ---------------------------------------------------------------------------

#define NPB 32           // nodes per bucket
#define NPB_SHIFT 5

__global__ void k_init(int* __restrict__ cnt, int N, int* __restrict__ flag) {
  int i = blockIdx.x * blockDim.x + threadIdx.x;
  if (i < N) cnt[i] = 0;
  if (i == 0) *flag = 1;  // assume int64 until proven otherwise
}

__global__ void k_detect(const int* __restrict__ e32, int twoE, int* __restrict__ flag) {
  int i = blockIdx.x * blockDim.x + threadIdx.x;
  if (i < 1024) {
    int idx = 2 * i + 1;  // odd int32 slots = high words if buffer is int64
    if (idx < twoE && e32[idx] != 0) atomicAnd(flag, 0);  // int32 data
  }
}

__device__ __forceinline__ int load_edge(const int* e32, int idx, int is64) {
  if (is64) return (int)((const long long*)e32)[idx];
  return e32[idx];
}

__global__ void k_hist(const int* __restrict__ e32, int E, int* __restrict__ cnt,
                       const int* __restrict__ flag) {
  int i = blockIdx.x * blockDim.x + threadIdx.x;
  if (i >= E) return;
  int is64 = *flag;
  int d = load_edge(e32, E + i, is64);
  atomicAdd(&cnt[d], 1);
}

__global__ void k_dinv(const int* __restrict__ cnt, float* __restrict__ dinv, int N) {
  int i = blockIdx.x * blockDim.x + threadIdx.x;
  if (i < N) dinv[i] = rsqrtf((float)cnt[i] + 1.0f);  // +1 = self-loop
}

// ---- exclusive scan of cnt -> rowptr (3-pass, 1024 elems/block) ----
__global__ void k_scan1(const int* __restrict__ cnt, int N, int* __restrict__ rowptr,
                        int* __restrict__ partial) {
  __shared__ int sh[256];
  const int t = threadIdx.x;
  const int base = blockIdx.x * 1024 + t * 4;
  int v0 = (base + 0 < N) ? cnt[base + 0] : 0;
  int v1 = (base + 1 < N) ? cnt[base + 1] : 0;
  int v2 = (base + 2 < N) ? cnt[base + 2] : 0;
  int v3 = (base + 3 < N) ? cnt[base + 3] : 0;
  int s = v0 + v1 + v2 + v3;
  sh[t] = s;
  __syncthreads();
  for (int off = 1; off < 256; off <<= 1) {
    int add = (t >= off) ? sh[t - off] : 0;
    __syncthreads();
    sh[t] += add;
    __syncthreads();
  }
  int excl = sh[t] - s;
  if (base + 0 < N) rowptr[base + 0] = excl;
  if (base + 1 < N) rowptr[base + 1] = excl + v0;
  if (base + 2 < N) rowptr[base + 2] = excl + v0 + v1;
  if (base + 3 < N) rowptr[base + 3] = excl + v0 + v1 + v2;
  if (t == 255) partial[blockIdx.x] = sh[255];
}

__global__ void k_scan2(int* __restrict__ partial, int NB) {
  __shared__ int sh[256];
  int t = threadIdx.x;
  int v = (t < NB) ? partial[t] : 0;
  sh[t] = v;
  __syncthreads();
  for (int off = 1; off < 256; off <<= 1) {
    int add = (t >= off) ? sh[t - off] : 0;
    __syncthreads();
    sh[t] += add;
    __syncthreads();
  }
  if (t < NB) partial[t] = sh[t] - v;  // exclusive
}

__global__ void k_scan3(int* __restrict__ rowptr, const int* __restrict__ partial,
                        int N, int E) {
  int i = blockIdx.x * blockDim.x + threadIdx.x;
  if (i < N) rowptr[i] = rowptr[i] + partial[i >> 10];
  if (i == 0) rowptr[N] = E;
}

__global__ void k_binit(const int* __restrict__ rowptr, int* __restrict__ bcur,
                        int nbuckets) {
  int b = blockIdx.x * blockDim.x + threadIdx.x;
  if (b < nbuckets) bcur[b] = rowptr[b << NPB_SHIFT];
}

__global__ void k_fill2(const int* __restrict__ e32, int E, int* __restrict__ bcur,
                        unsigned int* __restrict__ rec, const int* __restrict__ flag) {
  int i = blockIdx.x * blockDim.x + threadIdx.x;
  if (i >= E) return;
  int is64 = *flag;
  int s = load_edge(e32, i, is64);
  int d = load_edge(e32, E + i, is64);
  int pos = atomicAdd(&bcur[d >> NPB_SHIFT], 1);
  rec[pos] = ((unsigned int)(d & (NPB - 1)) << 25) | (unsigned int)s;
}

// ---- dense transform H[N][COUT] = X[N][CIN] @ W[CIN][COUT] ----
// Block = 256 threads = NODES x Q (Q = COUT/4 float4-quads per row).
// W fully staged in LDS; X tile staged padded. 1 output float4 per thread.
template <int CIN, int COUT>
__global__ void k_gemm(const float* __restrict__ X, const float* __restrict__ W,
                       float* __restrict__ H, int N) {
  constexpr int Q = COUT / 4;
  constexpr int NODES = 256 / Q;
  __shared__ float4 Ws[CIN * Q];
  __shared__ float Xs[NODES][CIN + 1];
  const int t = threadIdx.x;
  const int nodebase = blockIdx.x * NODES;

  const float4* W4 = (const float4*)W;
#pragma unroll
  for (int i = t; i < CIN * Q; i += 256) Ws[i] = W4[i];

  const float4* X4 = (const float4*)X;
#pragma unroll
  for (int i = t; i < NODES * (CIN / 4); i += 256) {
    int r = i / (CIN / 4);
    int k4 = i % (CIN / 4);
    int gr = nodebase + r;
    if (gr > N - 1) gr = N - 1;  // tail clamp (dup reads, harmless)
    float4 v = X4[(size_t)gr * (CIN / 4) + k4];
    Xs[r][k4 * 4 + 0] = v.x;
    Xs[r][k4 * 4 + 1] = v.y;
    Xs[r][k4 * 4 + 2] = v.z;
    Xs[r][k4 * 4 + 3] = v.w;
  }
  __syncthreads();

  const int q = t % Q;
  const int nl = t / Q;
  float4 acc = make_float4(0.f, 0.f, 0.f, 0.f);
#pragma unroll 4
  for (int k = 0; k < CIN; ++k) {
    float xv = Xs[nl][k];
    float4 wv = Ws[k * Q + q];
    acc.x = fmaf(xv, wv.x, acc.x);
    acc.y = fmaf(xv, wv.y, acc.y);
    acc.z = fmaf(xv, wv.z, acc.z);
    acc.w = fmaf(xv, wv.w, acc.w);
  }
  const int n = nodebase + nl;
  if (n < N) ((float4*)H)[(size_t)n * Q + q] = acc;
}

// ---- push-style propagation: one block per bucket, LDS accumulator ----
// out[n] = sum_{edges->n} w*H[src] + dinv[n]^2*H[n] + bias  (ReLU for layer 1)
template <int C, bool RELU>
__global__ void k_push(const float* __restrict__ H, const unsigned int* __restrict__ rec,
                       const int* __restrict__ rowptr, const float* __restrict__ dinv,
                       const float* __restrict__ bias, float* __restrict__ out, int N) {
  constexpr int U = 4;  // edge-slots unrolled per wave
  __shared__ float acc[NPB][C];
  const int b = blockIdx.x;
  const int nodebase = b << NPB_SHIFT;
  const int t = threadIdx.x;
  const int wid = t >> 6;
  const int lane = t & 63;

#pragma unroll
  for (int i = t; i < NPB * C; i += 256) ((float*)acc)[i] = 0.f;
  __syncthreads();

  int nend = nodebase + NPB;
  if (nend > N) nend = N;
  const int beg = rowptr[nodebase];
  const int end = rowptr[nend];

  if (C == 64) {
    // wave = one edge per slot; lane = channel
    for (int e = beg + wid * U; e < end; e += 4 * U) {
      float hv[U], wg[U];
      int dl[U];
#pragma unroll
      for (int u = 0; u < U; ++u) {
        int ee = e + u;
        dl[u] = -1;
        if (ee < end) {
          unsigned int r = rec[ee];
          int s = (int)(r & 0x1FFFFFFu);
          dl[u] = (int)(r >> 25);
          wg[u] = dinv[s] * dinv[nodebase + dl[u]];
          hv[u] = H[(size_t)s * C + lane];
        }
      }
#pragma unroll
      for (int u = 0; u < U; ++u)
        if (dl[u] >= 0) atomicAdd(&acc[dl[u]][lane], wg[u] * hv[u]);
    }
  } else {
    // C == 32: each half-wave handles its own edge; lane&31 = channel
    const int half = lane >> 5;
    const int c = lane & 31;
    for (int e = beg + wid * 2 * U; e < end; e += 8 * U) {
      float hv[U], wg[U];
      int dl[U];
#pragma unroll
      for (int u = 0; u < U; ++u) {
        int ee = e + 2 * u + half;
        dl[u] = -1;
        if (ee < end) {
          unsigned int r = rec[ee];
          int s = (int)(r & 0x1FFFFFFu);
          dl[u] = (int)(r >> 25);
          wg[u] = dinv[s] * dinv[nodebase + dl[u]];
          hv[u] = H[(size_t)s * C + c];
        }
      }
#pragma unroll
      for (int u = 0; u < U; ++u)
        if (dl[u] >= 0) atomicAdd(&acc[dl[u]][c], wg[u] * hv[u]);
    }
  }
  __syncthreads();

  // epilogue: add self-loop + bias, optional ReLU, coalesced store
#pragma unroll
  for (int i = t; i < NPB * C; i += 256) {
    int nl = i / C;
    int c = i % C;
    int n = nodebase + nl;
    if (n < N) {
      float di = dinv[n];
      float v = acc[nl][c] + H[(size_t)n * C + c] * (di * di) + bias[c];
      if (RELU) v = fmaxf(v, 0.f);
      out[(size_t)n * C + c] = v;
    }
  }
}

extern "C" void kernel_launch(void* const* d_in, const int* in_sizes, int n_in,
                              void* d_out, int out_size, void* d_ws, size_t ws_size,
                              hipStream_t stream) {
  (void)n_in; (void)out_size; (void)ws_size;
  const float* x = (const float*)d_in[0];
  const int* edges = (const int*)d_in[1];
  const float* W1 = (const float*)d_in[2];
  const float* b1 = (const float*)d_in[3];
  const float* W2 = (const float*)d_in[4];
  const float* b2 = (const float*)d_in[5];

  const int N = in_sizes[0] / 64;
  const int E = in_sizes[1] / 2;
  const int nbuckets = (N + NPB - 1) / NPB;

  // workspace carve-up (256B aligned)
  char* ws = (char*)d_ws;
  size_t off = 0;
  auto carve = [&](size_t bytes) -> void* {
    void* p = ws + off;
    off = (off + bytes + 255) & ~(size_t)255;
    return p;
  };
  int* flag          = (int*)carve(4);
  int* cnt           = (int*)carve((size_t)N * 4);
  int* rowptr        = (int*)carve((size_t)(N + 1) * 4);
  int* bcur          = (int*)carve((size_t)nbuckets * 4);
  float* dinv        = (float*)carve((size_t)N * 4);
  int* partial       = (int*)carve(1024);
  unsigned int* rec  = (unsigned int*)carve((size_t)E * 4);
  float* h1          = (float*)carve((size_t)N * 64 * 4);
  float* g1          = (float*)carve((size_t)N * 64 * 4);
  float* h2          = (float*)carve((size_t)N * 32 * 4);

  const int nbN = (N + 255) / 256;
  const int nbE = (E + 255) / 256;
  const int NB = (N + 1023) / 1024;  // must be <= 256 (N <= 262144)

  k_init<<<nbN, 256, 0, stream>>>(cnt, N, flag);
  k_detect<<<4, 256, 0, stream>>>(edges, 2 * E, flag);
  k_hist<<<nbE, 256, 0, stream>>>(edges, E, cnt, flag);
  k_dinv<<<nbN, 256, 0, stream>>>(cnt, dinv, N);
  k_scan1<<<NB, 256, 0, stream>>>(cnt, N, rowptr, partial);
  k_scan2<<<1, 256, 0, stream>>>(partial, NB);
  k_scan3<<<nbN, 256, 0, stream>>>(rowptr, partial, N, E);
  k_binit<<<(nbuckets + 255) / 256, 256, 0, stream>>>(rowptr, bcur, nbuckets);
  k_fill2<<<nbE, 256, 0, stream>>>(edges, E, bcur, rec, flag);

  k_gemm<64, 64><<<(N + 15) / 16, 256, 0, stream>>>(x, W1, h1, N);
  k_push<64, true><<<nbuckets, 256, 0, stream>>>(h1, rec, rowptr, dinv, b1, g1, N);
  k_gemm<64, 32><<<(N + 31) / 32, 256, 0, stream>>>(g1, W2, h2, N);
  k_push<32, false><<<nbuckets, 256, 0, stream>>>(h2, rec, rowptr, dinv, b2,
                                                  (float*)d_out, N);
}

// Round 5
// 762.782 us; speedup vs baseline: 1.4609x; 1.4609x over previous
//
#include <hip/hip_runtime.h>
#include <hip/hip_fp16.h>
#include <cstdint>
#include <cstddef>

// ---------------------------------------------------------------------------
// GCN 2-layer: out = GCNConv2( relu( GCNConv1(x) ) )
// Pipeline (pull-style propagation, exact per-node CSR, fp16 feature storage):
//   k_hist  : per-node in-degree histogram
//   k_dinv  : dinv = rsqrt(deg+1)
//   scan    : exclusive scan cnt -> rowptr (exact per-node offsets)
//   k_binit : per-128-node-bucket append cursors (782 cursors, L2-resident)
//   k_gcur  : global per-node cursor copy (fallback path for k_sort)
//   k_fill2 : append 4B packed records (dlocal<<25 | src) at bucket cursors
//   k_sort  : per-bucket LDS counting sort -> exact per-node CSR (coalesced IO)
//   k_gemm  : H(fp16) = X @ W  (LDS-staged, 1 float4 per thread, no spills)
//   k_prop64/32 : pull gather, wave per dst node, predicated 8-wide unroll
// Edge dtype (int32 vs int64) detected on-device via high words.
// ---------------------------------------------------------------------------

#define SB 128          // nodes per sort bucket
#define SB_SHIFT 7
#define SCAP 3072       // LDS record capacity per bucket (mean 2048, +23 sigma)

__global__ void k_init(int* __restrict__ cnt, int N, int* __restrict__ flag) {
  int i = blockIdx.x * blockDim.x + threadIdx.x;
  if (i < N) cnt[i] = 0;
  if (i == 0) *flag = 1;  // assume int64 until proven otherwise
}

__global__ void k_detect(const int* __restrict__ e32, int twoE, int* __restrict__ flag) {
  int i = blockIdx.x * blockDim.x + threadIdx.x;
  if (i < 1024) {
    int idx = 2 * i + 1;  // odd int32 slots = high words if buffer is int64
    if (idx < twoE && e32[idx] != 0) atomicAnd(flag, 0);  // int32 data
  }
}

__device__ __forceinline__ int load_edge(const int* e32, int idx, int is64) {
  if (is64) return (int)((const long long*)e32)[idx];
  return e32[idx];
}

__global__ void k_hist(const int* __restrict__ e32, int E, int* __restrict__ cnt,
                       const int* __restrict__ flag) {
  int i = blockIdx.x * blockDim.x + threadIdx.x;
  if (i >= E) return;
  int is64 = *flag;
  int d = load_edge(e32, E + i, is64);
  atomicAdd(&cnt[d], 1);
}

__global__ void k_dinv(const int* __restrict__ cnt, float* __restrict__ dinv, int N) {
  int i = blockIdx.x * blockDim.x + threadIdx.x;
  if (i < N) dinv[i] = rsqrtf((float)cnt[i] + 1.0f);  // +1 = self-loop
}

// ---- exclusive scan of cnt -> rowptr (3-pass, 1024 elems/block) ----
__global__ void k_scan1(const int* __restrict__ cnt, int N, int* __restrict__ rowptr,
                        int* __restrict__ partial) {
  __shared__ int sh[256];
  const int t = threadIdx.x;
  const int base = blockIdx.x * 1024 + t * 4;
  int v0 = (base + 0 < N) ? cnt[base + 0] : 0;
  int v1 = (base + 1 < N) ? cnt[base + 1] : 0;
  int v2 = (base + 2 < N) ? cnt[base + 2] : 0;
  int v3 = (base + 3 < N) ? cnt[base + 3] : 0;
  int s = v0 + v1 + v2 + v3;
  sh[t] = s;
  __syncthreads();
  for (int off = 1; off < 256; off <<= 1) {
    int add = (t >= off) ? sh[t - off] : 0;
    __syncthreads();
    sh[t] += add;
    __syncthreads();
  }
  int excl = sh[t] - s;
  if (base + 0 < N) rowptr[base + 0] = excl;
  if (base + 1 < N) rowptr[base + 1] = excl + v0;
  if (base + 2 < N) rowptr[base + 2] = excl + v0 + v1;
  if (base + 3 < N) rowptr[base + 3] = excl + v0 + v1 + v2;
  if (t == 255) partial[blockIdx.x] = sh[255];
}

__global__ void k_scan2(int* __restrict__ partial, int NB) {
  __shared__ int sh[256];
  int t = threadIdx.x;
  int v = (t < NB) ? partial[t] : 0;
  sh[t] = v;
  __syncthreads();
  for (int off = 1; off < 256; off <<= 1) {
    int add = (t >= off) ? sh[t - off] : 0;
    __syncthreads();
    sh[t] += add;
    __syncthreads();
  }
  if (t < NB) partial[t] = sh[t] - v;  // exclusive
}

__global__ void k_scan3(int* __restrict__ rowptr, const int* __restrict__ partial,
                        int N, int E) {
  int i = blockIdx.x * blockDim.x + threadIdx.x;
  if (i < N) rowptr[i] = rowptr[i] + partial[i >> 10];
  if (i == 0) rowptr[N] = E;
}

__global__ void k_binit(const int* __restrict__ rowptr, int* __restrict__ bcur,
                        int nbuckets) {
  int b = blockIdx.x * blockDim.x + threadIdx.x;
  if (b < nbuckets) bcur[b] = rowptr[b << SB_SHIFT];
}

__global__ void k_gcur(const int* __restrict__ rowptr, int* __restrict__ gcur, int N) {
  int i = blockIdx.x * blockDim.x + threadIdx.x;
  if (i < N) gcur[i] = rowptr[i];
}

__global__ void k_fill2(const int* __restrict__ e32, int E, int* __restrict__ bcur,
                        unsigned int* __restrict__ raw, const int* __restrict__ flag) {
  int i = blockIdx.x * blockDim.x + threadIdx.x;
  if (i >= E) return;
  int is64 = *flag;
  int s = load_edge(e32, i, is64);
  int d = load_edge(e32, E + i, is64);
  int pos = atomicAdd(&bcur[d >> SB_SHIFT], 1);
  raw[pos] = ((unsigned int)(d & (SB - 1)) << 25) | (unsigned int)s;
}

// ---- per-bucket LDS counting sort: raw (bucket-grouped) -> rec (node-grouped)
__global__ void k_sort(const unsigned int* __restrict__ raw, const int* __restrict__ rowptr,
                       int* __restrict__ rec, int* __restrict__ gcur, int N) {
  __shared__ int srec[SCAP];
  __shared__ int ncur[SB];
  const int b = blockIdx.x;
  const int t = threadIdx.x;
  const int nodebase = b << SB_SHIFT;
  int nend = nodebase + SB;
  if (nend > N) nend = N;
  const int base = rowptr[nodebase];
  const int end = rowptr[nend];
  const int count = end - base;
  if (count <= SCAP) {
    for (int i = t; i < SB; i += 256) {
      int n = nodebase + i;
      ncur[i] = (n < nend) ? (rowptr[n] - base) : 0;  // local offsets
    }
    __syncthreads();
    for (int i = t; i < count; i += 256) {
      unsigned int r = raw[base + i];
      int dl = (int)(r >> 25);
      int s = (int)(r & 0x1FFFFFFu);
      int pos = atomicAdd(&ncur[dl], 1);
      srec[pos] = s;
    }
    __syncthreads();
    for (int i = t; i < count; i += 256) rec[base + i] = srec[i];
  } else {
    // statistically unreachable fallback: global per-node cursors
    for (int i = t; i < count; i += 256) {
      unsigned int r = raw[base + i];
      int dl = (int)(r >> 25);
      int s = (int)(r & 0x1FFFFFFu);
      int pos = atomicAdd(&gcur[nodebase + dl], 1);
      rec[pos] = s;
    }
  }
}

// ---- dense transform H16[N][COUT] = X[N][CIN] @ W[CIN][COUT], fp16 output ----
// Block = 256 threads = NODES x Q (Q = COUT/4 quads). W staged in LDS; X tile
// staged padded (fp32 or fp16 input). One float4 acc per thread: no spill.
template <int CIN, int COUT, bool IN16>
__global__ void k_gemm(const void* __restrict__ Xv, const float* __restrict__ W,
                       __half* __restrict__ H, int N) {
  constexpr int Q = COUT / 4;
  constexpr int NODES = 256 / Q;
  __shared__ float4 Ws[CIN * Q];
  __shared__ float Xs[NODES][CIN + 1];
  const int t = threadIdx.x;
  const int nodebase = blockIdx.x * NODES;

  const float4* W4 = (const float4*)W;
#pragma unroll
  for (int i = t; i < CIN * Q; i += 256) Ws[i] = W4[i];

  if (IN16) {
    const __half2* X2 = (const __half2*)Xv;
#pragma unroll
    for (int i = t; i < NODES * (CIN / 2); i += 256) {
      int r = i / (CIN / 2);
      int k2 = i % (CIN / 2);
      int gr = nodebase + r;
      if (gr > N - 1) gr = N - 1;
      float2 f = __half22float2(X2[(size_t)gr * (CIN / 2) + k2]);
      Xs[r][k2 * 2 + 0] = f.x;
      Xs[r][k2 * 2 + 1] = f.y;
    }
  } else {
    const float4* X4 = (const float4*)Xv;
#pragma unroll
    for (int i = t; i < NODES * (CIN / 4); i += 256) {
      int r = i / (CIN / 4);
      int k4 = i % (CIN / 4);
      int gr = nodebase + r;
      if (gr > N - 1) gr = N - 1;
      float4 v = X4[(size_t)gr * (CIN / 4) + k4];
      Xs[r][k4 * 4 + 0] = v.x;
      Xs[r][k4 * 4 + 1] = v.y;
      Xs[r][k4 * 4 + 2] = v.z;
      Xs[r][k4 * 4 + 3] = v.w;
    }
  }
  __syncthreads();

  const int q = t % Q;
  const int nl = t / Q;
  float4 acc = make_float4(0.f, 0.f, 0.f, 0.f);
#pragma unroll 4
  for (int k = 0; k < CIN; ++k) {
    float xv = Xs[nl][k];
    float4 wv = Ws[k * Q + q];
    acc.x = fmaf(xv, wv.x, acc.x);
    acc.y = fmaf(xv, wv.y, acc.y);
    acc.z = fmaf(xv, wv.z, acc.z);
    acc.w = fmaf(xv, wv.w, acc.w);
  }
  const int n = nodebase + nl;
  if (n < N) {
    __half2* H2 = (__half2*)H;
    H2[(size_t)n * (COUT / 2) + 2 * q + 0] = __floats2half2_rn(acc.x, acc.y);
    H2[(size_t)n * (COUT / 2) + 2 * q + 1] = __floats2half2_rn(acc.z, acc.w);
  }
}

// ---- pull propagation, C=64: wave per dst node, lane = channel ----
// Predicated 8-wide edge loop: 8 independent 128B row-gathers in flight.
__global__ void k_prop64(const __half* __restrict__ H, const int* __restrict__ rec,
                         const int* __restrict__ rowptr, const float* __restrict__ dinv,
                         const float* __restrict__ bias, __half* __restrict__ out, int N) {
  const int gid = blockIdx.x * blockDim.x + threadIdx.x;
  const int n = gid >> 6;
  const int c = threadIdx.x & 63;
  if (n >= N) return;
  const float di = dinv[n];
  const int beg = rowptr[n];
  const int end = rowptr[n + 1];
  float av[4];
  av[0] = __half2float(H[(size_t)n * 64 + c]) * (di * di);  // self-loop
  av[1] = 0.f; av[2] = 0.f; av[3] = 0.f;
  for (int e = beg; e < end; e += 8) {
#pragma unroll
    for (int u = 0; u < 8; ++u) {
      int ee = e + u;
      bool ok = ee < end;
      int s = ok ? rec[ee] : 0;               // select -> inactive gathers H[0]
      float w = ok ? dinv[s] * di : 0.f;
      float hv = __half2float(H[(size_t)s * 64 + c]);
      av[u & 3] = fmaf(w, hv, av[u & 3]);
    }
  }
  float v = av[0] + av[1] + av[2] + av[3] + bias[c];
  v = fmaxf(v, 0.f);  // ReLU (layer 1)
  out[(size_t)n * 64 + c] = __float2half_rn(v);
}

// ---- pull propagation, C=32: wave per dst node, half-waves split edges ----
__global__ void k_prop32(const __half* __restrict__ H, const int* __restrict__ rec,
                         const int* __restrict__ rowptr, const float* __restrict__ dinv,
                         const float* __restrict__ bias, float* __restrict__ out, int N) {
  const int gid = blockIdx.x * blockDim.x + threadIdx.x;
  const int n = gid >> 6;
  const int lane = threadIdx.x & 63;
  if (n >= N) return;
  const int half = lane >> 5;
  const int c = lane & 31;
  const float di = dinv[n];
  const int beg = rowptr[n];
  const int end = rowptr[n + 1];
  float av[4];
  av[0] = half ? 0.f : __half2float(H[(size_t)n * 32 + c]) * (di * di);
  av[1] = 0.f; av[2] = 0.f; av[3] = 0.f;
  for (int e = beg + half; e < end; e += 8) {
#pragma unroll
    for (int u = 0; u < 4; ++u) {
      int ee = e + 2 * u;
      bool ok = ee < end;
      int s = ok ? rec[ee] : 0;
      float w = ok ? dinv[s] * di : 0.f;
      float hv = __half2float(H[(size_t)s * 32 + c]);
      av[u] = fmaf(w, hv, av[u]);
    }
  }
  float v = av[0] + av[1] + av[2] + av[3];
  v += __shfl_xor(v, 32);  // combine half-wave partial sums
  if (half) return;        // lower half writes
  out[(size_t)n * 32 + c] = v + bias[c];
}

extern "C" void kernel_launch(void* const* d_in, const int* in_sizes, int n_in,
                              void* d_out, int out_size, void* d_ws, size_t ws_size,
                              hipStream_t stream) {
  (void)n_in; (void)out_size; (void)ws_size;
  const float* x = (const float*)d_in[0];
  const int* edges = (const int*)d_in[1];
  const float* W1 = (const float*)d_in[2];
  const float* b1 = (const float*)d_in[3];
  const float* W2 = (const float*)d_in[4];
  const float* b2 = (const float*)d_in[5];

  const int N = in_sizes[0] / 64;
  const int E = in_sizes[1] / 2;
  const int nbuckets = (N + SB - 1) / SB;

  // workspace carve-up (256B aligned)
  char* ws = (char*)d_ws;
  size_t off = 0;
  auto carve = [&](size_t bytes) -> void* {
    void* p = ws + off;
    off = (off + bytes + 255) & ~(size_t)255;
    return p;
  };
  int* flag          = (int*)carve(4);
  int* cnt           = (int*)carve((size_t)N * 4);
  int* rowptr        = (int*)carve((size_t)(N + 1) * 4);
  int* bcur          = (int*)carve((size_t)nbuckets * 4);
  int* gcur          = (int*)carve((size_t)N * 4);
  float* dinv        = (float*)carve((size_t)N * 4);
  int* partial       = (int*)carve(1024);
  unsigned int* raw  = (unsigned int*)carve((size_t)E * 4);
  int* rec           = (int*)carve((size_t)E * 4);
  __half* h1         = (__half*)carve((size_t)N * 64 * 2);
  __half* g1         = (__half*)carve((size_t)N * 64 * 2);
  __half* h2         = (__half*)carve((size_t)N * 32 * 2);

  const int nbN = (N + 255) / 256;
  const int nbE = (E + 255) / 256;
  const int NB = (N + 1023) / 1024;  // must be <= 256 (N <= 262144)

  k_init<<<nbN, 256, 0, stream>>>(cnt, N, flag);
  k_detect<<<4, 256, 0, stream>>>(edges, 2 * E, flag);
  k_hist<<<nbE, 256, 0, stream>>>(edges, E, cnt, flag);
  k_dinv<<<nbN, 256, 0, stream>>>(cnt, dinv, N);
  k_scan1<<<NB, 256, 0, stream>>>(cnt, N, rowptr, partial);
  k_scan2<<<1, 256, 0, stream>>>(partial, NB);
  k_scan3<<<nbN, 256, 0, stream>>>(rowptr, partial, N, E);
  k_binit<<<(nbuckets + 255) / 256, 256, 0, stream>>>(rowptr, bcur, nbuckets);
  k_gcur<<<nbN, 256, 0, stream>>>(rowptr, gcur, N);
  k_fill2<<<nbE, 256, 0, stream>>>(edges, E, bcur, raw, flag);
  k_sort<<<nbuckets, 256, 0, stream>>>(raw, rowptr, rec, gcur, N);

  k_gemm<64, 64, false><<<(N + 15) / 16, 256, 0, stream>>>(x, W1, h1, N);
  k_prop64<<<(N + 3) / 4, 256, 0, stream>>>(h1, rec, rowptr, dinv, b1, g1, N);
  k_gemm<64, 32, true><<<(N + 31) / 32, 256, 0, stream>>>(g1, W2, h2, N);
  k_prop32<<<(N + 3) / 4, 256, 0, stream>>>(h2, rec, rowptr, dinv, b2,
                                            (float*)d_out, N);
}

// Round 6
// 295.726 us; speedup vs baseline: 3.7681x; 2.5794x over previous
//
#include <hip/hip_runtime.h>
#include <hip/hip_fp16.h>
#include <cstdint>
#include <cstddef>

// ---------------------------------------------------------------------------
// GCN 2-layer: out = GCNConv2( relu( GCNConv1(x) ) )
// Build (atomic-free radix partition -> per-node CSR):
//   k_hist/k_dinv/scan : degree, dinv, node-level rowptr
//   k_parthist : per-chunk LDS histogram over 256-node buckets (no gl atomics)
//   k_colscan  : per-bucket scan over chunks -> exact (chunk,bucket) offsets
//   k_scatter  : LDS re-bin + coalesced run flush into bucket-grouped raw[]
//   k_sort     : per-bucket LDS counting sort -> per-node CSR rec[]
// Compute:
//   k_gemm : Hs(fp16) = (X @ W) * dinv[row]  (norm folded into epilogue)
//   k_prop : out[n] = dinv[n]*(sum_e Hs[src] + Hs[n]) + bias  (pull, half2)
// Edge dtype (int32 vs int64) detected on-device via high words.
// ---------------------------------------------------------------------------

#define CHUNK 4096      // edges per partition block
#define BKN 256         // nodes per bucket
#define BKN_SHIFT 8
#define NCH_MAX 512     // max chunks (E <= 2.09M) / max buckets (N <= 131072)
#define SCAP2 5120      // LDS cap per bucket in k_sort (mean 4096, +16 sigma)

__global__ void k_init(int* __restrict__ cnt, int N, int* __restrict__ flag) {
  int i = blockIdx.x * blockDim.x + threadIdx.x;
  if (i < N) cnt[i] = 0;
  if (i == 0) *flag = 1;  // assume int64 until proven otherwise
}

__global__ void k_detect(const int* __restrict__ e32, int twoE, int* __restrict__ flag) {
  int i = blockIdx.x * blockDim.x + threadIdx.x;
  if (i < 1024) {
    int idx = 2 * i + 1;  // odd int32 slots = high words if buffer is int64
    if (idx < twoE && e32[idx] != 0) atomicAnd(flag, 0);  // int32 data
  }
}

__device__ __forceinline__ int load_edge(const int* e32, int idx, int is64) {
  if (is64) return (int)((const long long*)e32)[idx];
  return e32[idx];
}

__global__ void k_hist(const int* __restrict__ e32, int E, int* __restrict__ cnt,
                       const int* __restrict__ flag) {
  int i = blockIdx.x * blockDim.x + threadIdx.x;
  if (i >= E) return;
  int is64 = *flag;
  int d = load_edge(e32, E + i, is64);
  atomicAdd(&cnt[d], 1);  // 100k counters -> ~16 collisions each, cheap
}

__global__ void k_dinv(const int* __restrict__ cnt, float* __restrict__ dinv, int N) {
  int i = blockIdx.x * blockDim.x + threadIdx.x;
  if (i < N) dinv[i] = rsqrtf((float)cnt[i] + 1.0f);  // +1 = self-loop
}

// ---- exclusive scan of cnt -> rowptr (3-pass, 1024 elems/block) ----
__global__ void k_scan1(const int* __restrict__ cnt, int N, int* __restrict__ rowptr,
                        int* __restrict__ partial) {
  __shared__ int sh[256];
  const int t = threadIdx.x;
  const int base = blockIdx.x * 1024 + t * 4;
  int v0 = (base + 0 < N) ? cnt[base + 0] : 0;
  int v1 = (base + 1 < N) ? cnt[base + 1] : 0;
  int v2 = (base + 2 < N) ? cnt[base + 2] : 0;
  int v3 = (base + 3 < N) ? cnt[base + 3] : 0;
  int s = v0 + v1 + v2 + v3;
  sh[t] = s;
  __syncthreads();
  for (int off = 1; off < 256; off <<= 1) {
    int add = (t >= off) ? sh[t - off] : 0;
    __syncthreads();
    sh[t] += add;
    __syncthreads();
  }
  int excl = sh[t] - s;
  if (base + 0 < N) rowptr[base + 0] = excl;
  if (base + 1 < N) rowptr[base + 1] = excl + v0;
  if (base + 2 < N) rowptr[base + 2] = excl + v0 + v1;
  if (base + 3 < N) rowptr[base + 3] = excl + v0 + v1 + v2;
  if (t == 255) partial[blockIdx.x] = sh[255];
}

__global__ void k_scan2(int* __restrict__ partial, int NB) {
  __shared__ int sh[256];
  int t = threadIdx.x;
  int v = (t < NB) ? partial[t] : 0;
  sh[t] = v;
  __syncthreads();
  for (int off = 1; off < 256; off <<= 1) {
    int add = (t >= off) ? sh[t - off] : 0;
    __syncthreads();
    sh[t] += add;
    __syncthreads();
  }
  if (t < NB) partial[t] = sh[t] - v;  // exclusive
}

__global__ void k_scan3(int* __restrict__ rowptr, const int* __restrict__ partial,
                        int N, int E) {
  int i = blockIdx.x * blockDim.x + threadIdx.x;
  if (i < N) rowptr[i] = rowptr[i] + partial[i >> 10];
  if (i == 0) rowptr[N] = E;
}

__global__ void k_gcur(const int* __restrict__ rowptr, int* __restrict__ gcur, int N) {
  int i = blockIdx.x * blockDim.x + threadIdx.x;
  if (i < N) gcur[i] = rowptr[i];
}

// inclusive Hillis-Steele over 512 LDS slots with 256 threads
__device__ __forceinline__ void block_scan512(int* sh, int t) {
  for (int off = 1; off < 512; off <<= 1) {
    int i0 = t, i1 = t + 256;
    int v0 = sh[i0] + ((i0 >= off) ? sh[i0 - off] : 0);
    int v1 = sh[i1] + ((i1 >= off) ? sh[i1 - off] : 0);
    __syncthreads();
    sh[i0] = v0;
    sh[i1] = v1;
    __syncthreads();
  }
}

// ---- partition pass A: per-chunk histogram over buckets (LDS only) ----
__global__ void k_parthist(const int* __restrict__ e32, int E, int* __restrict__ histM,
                           int NCH, int NBUCK, const int* __restrict__ flag) {
  __shared__ int lh[NCH_MAX];
  const int c = blockIdx.x;
  const int t = threadIdx.x;
  for (int i = t; i < NBUCK; i += 256) lh[i] = 0;
  __syncthreads();
  const int is64 = *flag;
  const int beg = c * CHUNK;
  const int cnt = min(CHUNK, E - beg);
  for (int i = t; i < cnt; i += 256) {
    int d = load_edge(e32, E + beg + i, is64);
    atomicAdd(&lh[d >> BKN_SHIFT], 1);  // LDS atomic: on-CU, cheap
  }
  __syncthreads();
  for (int i = t; i < NBUCK; i += 256) histM[(size_t)i * NCH + c] = lh[i];
}

// ---- partition pass B: per-bucket scan over chunks -> global offsets ----
__global__ void k_colscan(int* __restrict__ histM, const int* __restrict__ rowptr,
                          int NCH, int N) {
  __shared__ int sh[NCH_MAX];
  const int b = blockIdx.x;
  const int t = threadIdx.x;
  for (int i = t; i < NCH_MAX; i += 256) sh[i] = (i < NCH) ? histM[(size_t)b * NCH + i] : 0;
  __syncthreads();
  block_scan512(sh, t);  // inclusive
  const int base = rowptr[b << BKN_SHIFT];
  for (int i = t; i < NCH; i += 256) {
    int excl = (i == 0) ? 0 : sh[i - 1];
    histM[(size_t)b * NCH + i] = base + excl;
  }
}

// ---- partition pass C: LDS re-bin + coalesced run flush ----
__global__ void k_scatter(const int* __restrict__ e32, int E, const int* __restrict__ histM,
                          int NCH, int NBUCK, unsigned int* __restrict__ raw,
                          const int* __restrict__ flag) {
  __shared__ int loff[NCH_MAX + 1];
  __shared__ int lcur[NCH_MAX];
  __shared__ int lofg[NCH_MAX];
  __shared__ unsigned int srec[CHUNK];
  const int c = blockIdx.x;
  const int t = threadIdx.x;
  for (int i = t; i < NCH_MAX; i += 256) lcur[i] = 0;
  __syncthreads();
  const int is64 = *flag;
  const int beg = c * CHUNK;
  const int cnt = min(CHUNK, E - beg);
  // histogram into lcur
  for (int i = t; i < cnt; i += 256) {
    int d = load_edge(e32, E + beg + i, is64);
    atomicAdd(&lcur[d >> BKN_SHIFT], 1);
  }
  // stage this chunk's global offsets (one strided read per bucket)
  for (int i = t; i < NBUCK; i += 256) lofg[i] = histM[(size_t)i * NCH + c];
  __syncthreads();
  // exclusive scan of lcur -> loff
  for (int i = t; i < NCH_MAX; i += 256) loff[i] = lcur[i];
  __syncthreads();
  block_scan512(loff, t);  // inclusive
  {
    int e0 = (t == 0) ? 0 : loff[t - 1];
    int e1 = loff[t + 255];
    __syncthreads();
    loff[t] = e0;
    loff[t + 256] = e1;
    if (t == 0) loff[NCH_MAX] = cnt;
    __syncthreads();
    for (int i = t; i < NCH_MAX; i += 256) lcur[i] = loff[i];  // cursors
  }
  __syncthreads();
  // place records grouped by bucket in LDS
  for (int i = t; i < cnt; i += 256) {
    int s = load_edge(e32, beg + i, is64);
    int d = load_edge(e32, E + beg + i, is64);
    int b = d >> BKN_SHIFT;
    int pos = atomicAdd(&lcur[b], 1);
    srec[pos] = ((unsigned int)(d & (BKN - 1)) << 23) | (unsigned int)s;
  }
  __syncthreads();
  // flush: binary search bucket of slot i, write to reserved range
  for (int i = t; i < cnt; i += 256) {
    int lo = 0, hi = NBUCK;
    while (hi - lo > 1) {
      int mid = (lo + hi) >> 1;
      if (loff[mid] <= i) lo = mid; else hi = mid;
    }
    raw[lofg[lo] + (i - loff[lo])] = srec[i];
  }
}

// ---- per-bucket LDS counting sort: raw (bucket-grouped) -> rec (per-node) ----
__global__ void k_sort(const unsigned int* __restrict__ raw, const int* __restrict__ rowptr,
                       int* __restrict__ rec, int* __restrict__ gcur, int N) {
  __shared__ int srec[SCAP2];
  __shared__ int ncur[BKN];
  const int b = blockIdx.x;
  const int t = threadIdx.x;
  const int nodebase = b << BKN_SHIFT;
  const int nend = min(nodebase + BKN, N);
  const int base = rowptr[nodebase];
  const int end = rowptr[nend];
  const int count = end - base;
  if (count <= SCAP2) {
    ncur[t] = (nodebase + t < nend) ? rowptr[nodebase + t] - base : 0;
    __syncthreads();
    for (int i = t; i < count; i += 256) {
      unsigned int r = raw[base + i];
      int pos = atomicAdd(&ncur[r >> 23], 1);
      srec[pos] = (int)(r & 0x7FFFFFu);
    }
    __syncthreads();
    for (int i = t; i < count; i += 256) rec[base + i] = srec[i];
  } else {  // statistically unreachable fallback
    for (int i = t; i < count; i += 256) {
      unsigned int r = raw[base + i];
      int pos = atomicAdd(&gcur[nodebase + (int)(r >> 23)], 1);
      rec[pos] = (int)(r & 0x7FFFFFu);
    }
  }
}

// ---- dense transform Hs[N][COUT] = (X[N][CIN] @ W) * dinv[row], fp16 out ----
template <int CIN, int COUT, bool IN16>
__global__ void k_gemm(const void* __restrict__ Xv, const float* __restrict__ W,
                       const float* __restrict__ dinv, __half* __restrict__ H, int N) {
  constexpr int Q = COUT / 4;
  constexpr int NODES = 256 / Q;
  __shared__ float4 Ws[CIN * Q];
  __shared__ float Xs[NODES][CIN + 1];
  const int t = threadIdx.x;
  const int nodebase = blockIdx.x * NODES;

  const float4* W4 = (const float4*)W;
#pragma unroll
  for (int i = t; i < CIN * Q; i += 256) Ws[i] = W4[i];

  if (IN16) {
    const __half2* X2 = (const __half2*)Xv;
#pragma unroll
    for (int i = t; i < NODES * (CIN / 2); i += 256) {
      int r = i / (CIN / 2);
      int k2 = i % (CIN / 2);
      int gr = nodebase + r;
      if (gr > N - 1) gr = N - 1;
      float2 f = __half22float2(X2[(size_t)gr * (CIN / 2) + k2]);
      Xs[r][k2 * 2 + 0] = f.x;
      Xs[r][k2 * 2 + 1] = f.y;
    }
  } else {
    const float4* X4 = (const float4*)Xv;
#pragma unroll
    for (int i = t; i < NODES * (CIN / 4); i += 256) {
      int r = i / (CIN / 4);
      int k4 = i % (CIN / 4);
      int gr = nodebase + r;
      if (gr > N - 1) gr = N - 1;
      float4 v = X4[(size_t)gr * (CIN / 4) + k4];
      Xs[r][k4 * 4 + 0] = v.x;
      Xs[r][k4 * 4 + 1] = v.y;
      Xs[r][k4 * 4 + 2] = v.z;
      Xs[r][k4 * 4 + 3] = v.w;
    }
  }
  __syncthreads();

  const int q = t % Q;
  const int nl = t / Q;
  const int n = nodebase + nl;
  float4 acc = make_float4(0.f, 0.f, 0.f, 0.f);
#pragma unroll 4
  for (int k = 0; k < CIN; ++k) {
    float xv = Xs[nl][k];
    float4 wv = Ws[k * Q + q];
    acc.x = fmaf(xv, wv.x, acc.x);
    acc.y = fmaf(xv, wv.y, acc.y);
    acc.z = fmaf(xv, wv.z, acc.z);
    acc.w = fmaf(xv, wv.w, acc.w);
  }
  if (n < N) {
    float dn = dinv[n];  // fold symmetric norm into stored features
    __half2* H2 = (__half2*)H;
    H2[(size_t)n * (COUT / 2) + 2 * q + 0] = __floats2half2_rn(acc.x * dn, acc.y * dn);
    H2[(size_t)n * (COUT / 2) + 2 * q + 1] = __floats2half2_rn(acc.z * dn, acc.w * dn);
  }
}

// ---- pull prop C=64: wave/node, half-waves split edges, half2 gathers ----
// out[n] = relu( dinv[n]*(sum_e Hs[src] + Hs[n]) + b )   (fp16 out)
__global__ void k_prop64(const __half2* __restrict__ H2, const int* __restrict__ rec,
                         const int* __restrict__ rowptr, const float* __restrict__ dinv,
                         const float* __restrict__ bias, __half* __restrict__ out, int N) {
  const int gid = blockIdx.x * blockDim.x + threadIdx.x;
  const int n = gid >> 6;
  if (n >= N) return;
  const int lane = threadIdx.x & 63;
  const int half = lane >> 5;
  const int c2 = lane & 31;
  const float di = dinv[n];
  const int beg = rowptr[n];
  const int end = rowptr[n + 1];
  float ax[4] = {0.f, 0.f, 0.f, 0.f}, ay[4] = {0.f, 0.f, 0.f, 0.f};
  if (half == 0) {
    float2 hv = __half22float2(H2[(size_t)n * 32 + c2]);  // self-loop term
    ax[0] = hv.x; ay[0] = hv.y;
  }
  for (int e = beg + half; e < end; e += 8) {
#pragma unroll
    for (int u = 0; u < 4; ++u) {
      int ee = e + 2 * u;
      bool ok = ee < end;
      int s = ok ? rec[ee] : 0;
      float2 hv = __half22float2(H2[(size_t)s * 32 + c2]);
      ax[u] += ok ? hv.x : 0.f;
      ay[u] += ok ? hv.y : 0.f;
    }
  }
  float vx = ax[0] + ax[1] + ax[2] + ax[3];
  float vy = ay[0] + ay[1] + ay[2] + ay[3];
  vx += __shfl_xor(vx, 32);
  vy += __shfl_xor(vy, 32);
  if (half) return;
  float2 bb = ((const float2*)bias)[c2];
  vx = fmaxf(fmaf(vx, di, bb.x), 0.f);
  vy = fmaxf(fmaf(vy, di, bb.y), 0.f);
  ((__half2*)out)[(size_t)n * 32 + c2] = __floats2half2_rn(vx, vy);
}

// ---- pull prop C=32: wave/node, quarter-waves split edges, fp32 out ----
__global__ void k_prop32(const __half2* __restrict__ H2, const int* __restrict__ rec,
                         const int* __restrict__ rowptr, const float* __restrict__ dinv,
                         const float* __restrict__ bias, float* __restrict__ out, int N) {
  const int gid = blockIdx.x * blockDim.x + threadIdx.x;
  const int n = gid >> 6;
  if (n >= N) return;
  const int lane = threadIdx.x & 63;
  const int q = lane >> 4;
  const int c2 = lane & 15;
  const float di = dinv[n];
  const int beg = rowptr[n];
  const int end = rowptr[n + 1];
  float ax[2] = {0.f, 0.f}, ay[2] = {0.f, 0.f};
  if (q == 0) {
    float2 hv = __half22float2(H2[(size_t)n * 16 + c2]);  // self-loop term
    ax[0] = hv.x; ay[0] = hv.y;
  }
  for (int e = beg + q; e < end; e += 8) {
#pragma unroll
    for (int u = 0; u < 2; ++u) {
      int ee = e + 4 * u;
      bool ok = ee < end;
      int s = ok ? rec[ee] : 0;
      float2 hv = __half22float2(H2[(size_t)s * 16 + c2]);
      ax[u] += ok ? hv.x : 0.f;
      ay[u] += ok ? hv.y : 0.f;
    }
  }
  float vx = ax[0] + ax[1];
  float vy = ay[0] + ay[1];
  vx += __shfl_xor(vx, 16); vx += __shfl_xor(vx, 32);
  vy += __shfl_xor(vy, 16); vy += __shfl_xor(vy, 32);
  if (q) return;
  float2 bb = ((const float2*)bias)[c2];
  ((float2*)out)[(size_t)n * 16 + c2] =
      make_float2(fmaf(vx, di, bb.x), fmaf(vy, di, bb.y));
}

extern "C" void kernel_launch(void* const* d_in, const int* in_sizes, int n_in,
                              void* d_out, int out_size, void* d_ws, size_t ws_size,
                              hipStream_t stream) {
  (void)n_in; (void)out_size; (void)ws_size;
  const float* x = (const float*)d_in[0];
  const int* edges = (const int*)d_in[1];
  const float* W1 = (const float*)d_in[2];
  const float* b1 = (const float*)d_in[3];
  const float* W2 = (const float*)d_in[4];
  const float* b2 = (const float*)d_in[5];

  const int N = in_sizes[0] / 64;
  const int E = in_sizes[1] / 2;
  const int NCH = (E + CHUNK - 1) / CHUNK;        // 391 (<= 512)
  const int NBUCK = (N + BKN - 1) / BKN;          // 391 (<= 512)

  // workspace carve-up (256B aligned)
  char* ws = (char*)d_ws;
  size_t off = 0;
  auto carve = [&](size_t bytes) -> void* {
    void* p = ws + off;
    off = (off + bytes + 255) & ~(size_t)255;
    return p;
  };
  int* flag          = (int*)carve(4);
  int* cnt           = (int*)carve((size_t)N * 4);
  int* rowptr        = (int*)carve((size_t)(N + 1) * 4);
  int* gcur          = (int*)carve((size_t)N * 4);
  float* dinv        = (float*)carve((size_t)N * 4);
  int* partial       = (int*)carve(1024);
  int* histM         = (int*)carve((size_t)NBUCK * NCH * 4);
  unsigned int* raw  = (unsigned int*)carve((size_t)E * 4);
  int* rec           = (int*)carve((size_t)E * 4);
  __half* h1         = (__half*)carve((size_t)N * 64 * 2);
  __half* g1         = (__half*)carve((size_t)N * 64 * 2);
  __half* h2         = (__half*)carve((size_t)N * 32 * 2);

  const int nbN = (N + 255) / 256;
  const int nbE = (E + 255) / 256;
  const int NB = (N + 1023) / 1024;  // must be <= 256 (N <= 262144)

  k_init<<<nbN, 256, 0, stream>>>(cnt, N, flag);
  k_detect<<<4, 256, 0, stream>>>(edges, 2 * E, flag);
  k_hist<<<nbE, 256, 0, stream>>>(edges, E, cnt, flag);
  k_dinv<<<nbN, 256, 0, stream>>>(cnt, dinv, N);
  k_scan1<<<NB, 256, 0, stream>>>(cnt, N, rowptr, partial);
  k_scan2<<<1, 256, 0, stream>>>(partial, NB);
  k_scan3<<<nbN, 256, 0, stream>>>(rowptr, partial, N, E);
  k_gcur<<<nbN, 256, 0, stream>>>(rowptr, gcur, N);

  k_parthist<<<NCH, 256, 0, stream>>>(edges, E, histM, NCH, NBUCK, flag);
  k_colscan<<<NBUCK, 256, 0, stream>>>(histM, rowptr, NCH, N);
  k_scatter<<<NCH, 256, 0, stream>>>(edges, E, histM, NCH, NBUCK, raw, flag);
  k_sort<<<NBUCK, 256, 0, stream>>>(raw, rowptr, rec, gcur, N);

  k_gemm<64, 64, false><<<(N + 15) / 16, 256, 0, stream>>>(x, W1, dinv, h1, N);
  k_prop64<<<(N + 3) / 4, 256, 0, stream>>>((const __half2*)h1, rec, rowptr, dinv,
                                            b1, g1, N);
  k_gemm<64, 32, true><<<(N + 31) / 32, 256, 0, stream>>>(g1, W2, dinv, h2, N);
  k_prop32<<<(N + 3) / 4, 256, 0, stream>>>((const __half2*)h2, rec, rowptr, dinv,
                                            b2, (float*)d_out, N);
}

// Round 7
// 275.589 us; speedup vs baseline: 4.0434x; 1.0731x over previous
//
#include <hip/hip_runtime.h>
#include <hip/hip_fp16.h>
#include <cstdint>
#include <cstddef>

// ---------------------------------------------------------------------------
// GCN 2-layer: out = GCNConv2( relu( GCNConv1(x) ) )
// Build (atomic-free radix partition -> per-node CSR):
//   k_histA   : one edge pass: per-node cnt atomics + per-chunk LDS bucket hist
//   k_scan1/2/3 : exclusive scan cnt -> rowptr; scan3 also emits dinv + gcur
//   k_colscan : per-bucket scan over chunks -> exact (chunk,bucket) write bases
//   k_scatter : direct scatter: LDS cursor per bucket, one global write/edge
//   k_sort    : per-bucket LDS counting sort -> per-node CSR rec[]
// Compute:
//   k_gemm : Hs(fp16) = (X @ W) * dinv[row]  (norm folded into epilogue)
//   k_prop : out[n] = dinv[n]*(sum_e Hs[src] + Hs[n]) + bias  (pull, half2,
//            deep-unrolled for 16 gathers in flight per wave)
// Edge dtype (int32 vs int64) detected on-device via high words.
// ---------------------------------------------------------------------------

#define CHUNK 4096      // edges per partition block
#define BKN 256         // nodes per bucket
#define BKN_SHIFT 8
#define NCH_MAX 512     // max chunks (E <= 2.09M) / max buckets (N <= 131072)
#define SCAP2 5120      // LDS cap per bucket in k_sort (mean 4096, +16 sigma)

__global__ void k_detect(const int* __restrict__ e32, int twoE, int* __restrict__ flag) {
  int i = blockIdx.x * blockDim.x + threadIdx.x;
  if (i < 1024) {
    int idx = 2 * i + 1;  // odd int32 slots = high words if buffer is int64
    if (idx < twoE && e32[idx] != 0) atomicAnd(flag, 0);  // int32 data
  }
}

__device__ __forceinline__ int load_edge(const int* e32, int idx, int is64) {
  if (is64) return (int)((const long long*)e32)[idx];
  return e32[idx];
}

// ---- fused edge pass: per-node degree atomics + per-chunk bucket histogram ----
__global__ void k_histA(const int* __restrict__ e32, int E, int* __restrict__ cnt,
                        int* __restrict__ histM, int NBUCK, const int* __restrict__ flag) {
  __shared__ int lh[NCH_MAX];
  const int c = blockIdx.x;
  const int t = threadIdx.x;
  for (int i = t; i < NBUCK; i += 256) lh[i] = 0;
  __syncthreads();
  const int is64 = *flag;
  const int beg = c * CHUNK;
  const int n = min(CHUNK, E - beg);
  for (int i = t; i < n; i += 256) {
    int d = load_edge(e32, E + beg + i, is64);
    atomicAdd(&cnt[d], 1);            // 100k counters -> ~16 collisions, cheap
    atomicAdd(&lh[d >> BKN_SHIFT], 1);  // LDS atomic: on-CU
  }
  __syncthreads();
  for (int i = t; i < NBUCK; i += 256) histM[(size_t)c * NBUCK + i] = lh[i];
}

// ---- exclusive scan of cnt -> rowptr (3-pass, 1024 elems/block) ----
__global__ void k_scan1(const int* __restrict__ cnt, int N, int* __restrict__ rowptr,
                        int* __restrict__ partial) {
  __shared__ int sh[256];
  const int t = threadIdx.x;
  const int base = blockIdx.x * 1024 + t * 4;
  int v0 = (base + 0 < N) ? cnt[base + 0] : 0;
  int v1 = (base + 1 < N) ? cnt[base + 1] : 0;
  int v2 = (base + 2 < N) ? cnt[base + 2] : 0;
  int v3 = (base + 3 < N) ? cnt[base + 3] : 0;
  int s = v0 + v1 + v2 + v3;
  sh[t] = s;
  __syncthreads();
  for (int off = 1; off < 256; off <<= 1) {
    int add = (t >= off) ? sh[t - off] : 0;
    __syncthreads();
    sh[t] += add;
    __syncthreads();
  }
  int excl = sh[t] - s;
  if (base + 0 < N) rowptr[base + 0] = excl;
  if (base + 1 < N) rowptr[base + 1] = excl + v0;
  if (base + 2 < N) rowptr[base + 2] = excl + v0 + v1;
  if (base + 3 < N) rowptr[base + 3] = excl + v0 + v1 + v2;
  if (t == 255) partial[blockIdx.x] = sh[255];
}

__global__ void k_scan2(int* __restrict__ partial, int NB) {
  __shared__ int sh[256];
  int t = threadIdx.x;
  int v = (t < NB) ? partial[t] : 0;
  sh[t] = v;
  __syncthreads();
  for (int off = 1; off < 256; off <<= 1) {
    int add = (t >= off) ? sh[t - off] : 0;
    __syncthreads();
    sh[t] += add;
    __syncthreads();
  }
  if (t < NB) partial[t] = sh[t] - v;  // exclusive
}

// scan3 fused: final rowptr + gcur copy + dinv compute
__global__ void k_scan3(int* __restrict__ rowptr, const int* __restrict__ partial,
                        const int* __restrict__ cnt, float* __restrict__ dinv,
                        int* __restrict__ gcur, int N, int E) {
  int i = blockIdx.x * blockDim.x + threadIdx.x;
  if (i < N) {
    int r = rowptr[i] + partial[i >> 10];
    rowptr[i] = r;
    gcur[i] = r;
    dinv[i] = rsqrtf((float)cnt[i] + 1.0f);  // +1 = self-loop
  }
  if (i == 0) rowptr[N] = E;
}

// inclusive Hillis-Steele over 512 LDS slots with 256 threads
__device__ __forceinline__ void block_scan512(int* sh, int t) {
  for (int off = 1; off < 512; off <<= 1) {
    int i0 = t, i1 = t + 256;
    int v0 = sh[i0] + ((i0 >= off) ? sh[i0 - off] : 0);
    int v1 = sh[i1] + ((i1 >= off) ? sh[i1 - off] : 0);
    __syncthreads();
    sh[i0] = v0;
    sh[i1] = v1;
    __syncthreads();
  }
}

// ---- per-bucket scan over chunks -> exact global write bases, in place ----
__global__ void k_colscan(int* __restrict__ histM, const int* __restrict__ rowptr,
                          int NCH, int NBUCK) {
  __shared__ int sh[NCH_MAX];
  const int b = blockIdx.x;
  const int t = threadIdx.x;
  for (int i = t; i < NCH_MAX; i += 256)
    sh[i] = (i < NCH) ? histM[(size_t)i * NBUCK + b] : 0;
  __syncthreads();
  block_scan512(sh, t);  // inclusive
  const int base = rowptr[b << BKN_SHIFT];
  for (int i = t; i < NCH; i += 256) {
    int excl = (i == 0) ? 0 : sh[i - 1];
    histM[(size_t)i * NBUCK + b] = base + excl;
  }
}

// ---- direct scatter: LDS cursor per bucket, one global write per edge ----
// Each chunk's records for bucket b land in a reserved contiguous run
// (~10 records), so writes cluster into L2-resident partial lines.
__global__ void k_scatter(const int* __restrict__ e32, int E, const int* __restrict__ histM,
                          int NBUCK, unsigned int* __restrict__ raw,
                          const int* __restrict__ flag) {
  __shared__ int lcur[NCH_MAX];
  const int c = blockIdx.x;
  const int t = threadIdx.x;
  for (int i = t; i < NBUCK; i += 256) lcur[i] = histM[(size_t)c * NBUCK + i];
  __syncthreads();
  const int is64 = *flag;
  const int beg = c * CHUNK;
  const int cnt = min(CHUNK, E - beg);
  for (int i = t; i < cnt; i += 256) {
    int s = load_edge(e32, beg + i, is64);
    int d = load_edge(e32, E + beg + i, is64);
    int pos = atomicAdd(&lcur[d >> BKN_SHIFT], 1);
    raw[pos] = ((unsigned int)(d & (BKN - 1)) << 23) | (unsigned int)s;
  }
}

// ---- per-bucket LDS counting sort: raw (bucket-grouped) -> rec (per-node) ----
__global__ void k_sort(const unsigned int* __restrict__ raw, const int* __restrict__ rowptr,
                       int* __restrict__ rec, int* __restrict__ gcur, int N) {
  __shared__ int srec[SCAP2];
  __shared__ int ncur[BKN];
  const int b = blockIdx.x;
  const int t = threadIdx.x;
  const int nodebase = b << BKN_SHIFT;
  const int nend = min(nodebase + BKN, N);
  const int base = rowptr[nodebase];
  const int end = rowptr[nend];
  const int count = end - base;
  if (count <= SCAP2) {
    ncur[t] = (nodebase + t < nend) ? rowptr[nodebase + t] - base : 0;
    __syncthreads();
    for (int i = t; i < count; i += 256) {
      unsigned int r = raw[base + i];
      int pos = atomicAdd(&ncur[r >> 23], 1);
      srec[pos] = (int)(r & 0x7FFFFFu);
    }
    __syncthreads();
    for (int i = t; i < count; i += 256) rec[base + i] = srec[i];
  } else {  // statistically unreachable fallback
    for (int i = t; i < count; i += 256) {
      unsigned int r = raw[base + i];
      int pos = atomicAdd(&gcur[nodebase + (int)(r >> 23)], 1);
      rec[pos] = (int)(r & 0x7FFFFFu);
    }
  }
}

// ---- dense transform Hs[N][COUT] = (X[N][CIN] @ W) * dinv[row], fp16 out ----
template <int CIN, int COUT, bool IN16>
__global__ void k_gemm(const void* __restrict__ Xv, const float* __restrict__ W,
                       const float* __restrict__ dinv, __half* __restrict__ H, int N) {
  constexpr int Q = COUT / 4;
  constexpr int NODES = 256 / Q;
  __shared__ float4 Ws[CIN * Q];
  __shared__ float Xs[NODES][CIN + 1];
  const int t = threadIdx.x;
  const int nodebase = blockIdx.x * NODES;

  const float4* W4 = (const float4*)W;
#pragma unroll
  for (int i = t; i < CIN * Q; i += 256) Ws[i] = W4[i];

  if (IN16) {
    const __half2* X2 = (const __half2*)Xv;
#pragma unroll
    for (int i = t; i < NODES * (CIN / 2); i += 256) {
      int r = i / (CIN / 2);
      int k2 = i % (CIN / 2);
      int gr = nodebase + r;
      if (gr > N - 1) gr = N - 1;
      float2 f = __half22float2(X2[(size_t)gr * (CIN / 2) + k2]);
      Xs[r][k2 * 2 + 0] = f.x;
      Xs[r][k2 * 2 + 1] = f.y;
    }
  } else {
    const float4* X4 = (const float4*)Xv;
#pragma unroll
    for (int i = t; i < NODES * (CIN / 4); i += 256) {
      int r = i / (CIN / 4);
      int k4 = i % (CIN / 4);
      int gr = nodebase + r;
      if (gr > N - 1) gr = N - 1;
      float4 v = X4[(size_t)gr * (CIN / 4) + k4];
      Xs[r][k4 * 4 + 0] = v.x;
      Xs[r][k4 * 4 + 1] = v.y;
      Xs[r][k4 * 4 + 2] = v.z;
      Xs[r][k4 * 4 + 3] = v.w;
    }
  }
  __syncthreads();

  const int q = t % Q;
  const int nl = t / Q;
  const int n = nodebase + nl;
  float4 acc = make_float4(0.f, 0.f, 0.f, 0.f);
#pragma unroll 4
  for (int k = 0; k < CIN; ++k) {
    float xv = Xs[nl][k];
    float4 wv = Ws[k * Q + q];
    acc.x = fmaf(xv, wv.x, acc.x);
    acc.y = fmaf(xv, wv.y, acc.y);
    acc.z = fmaf(xv, wv.z, acc.z);
    acc.w = fmaf(xv, wv.w, acc.w);
  }
  if (n < N) {
    float dn = dinv[n];  // fold symmetric norm into stored features
    __half2* H2 = (__half2*)H;
    H2[(size_t)n * (COUT / 2) + 2 * q + 0] = __floats2half2_rn(acc.x * dn, acc.y * dn);
    H2[(size_t)n * (COUT / 2) + 2 * q + 1] = __floats2half2_rn(acc.z * dn, acc.w * dn);
  }
}

// ---- pull prop C=64: wave/node, half-waves split edges, 8-deep unroll ----
// 16 independent 128B gathers in flight per wave. deg~16 -> one iteration.
__global__ void k_prop64(const __half2* __restrict__ H2, const int* __restrict__ rec,
                         const int* __restrict__ rowptr, const float* __restrict__ dinv,
                         const float* __restrict__ bias, __half* __restrict__ out, int N) {
  const int gid = blockIdx.x * blockDim.x + threadIdx.x;
  const int n = gid >> 6;
  if (n >= N) return;
  const int lane = threadIdx.x & 63;
  const int half = lane >> 5;
  const int c2 = lane & 31;
  const float di = dinv[n];
  const int beg = rowptr[n];
  const int end = rowptr[n + 1];
  float ax[4] = {0.f, 0.f, 0.f, 0.f}, ay[4] = {0.f, 0.f, 0.f, 0.f};
  if (half == 0) {
    float2 hv = __half22float2(H2[(size_t)n * 32 + c2]);  // self-loop term
    ax[0] = hv.x; ay[0] = hv.y;
  }
  for (int e = beg + half; e < end; e += 16) {
#pragma unroll
    for (int u = 0; u < 8; ++u) {
      int ee = e + 2 * u;
      bool ok = ee < end;
      int s = ok ? rec[ee] : 0;
      float2 hv = __half22float2(H2[(size_t)s * 32 + c2]);
      ax[u & 3] += ok ? hv.x : 0.f;
      ay[u & 3] += ok ? hv.y : 0.f;
    }
  }
  float vx = ax[0] + ax[1] + ax[2] + ax[3];
  float vy = ay[0] + ay[1] + ay[2] + ay[3];
  vx += __shfl_xor(vx, 32);
  vy += __shfl_xor(vy, 32);
  if (half) return;
  float2 bb = ((const float2*)bias)[c2];
  vx = fmaxf(fmaf(vx, di, bb.x), 0.f);
  vy = fmaxf(fmaf(vy, di, bb.y), 0.f);
  ((__half2*)out)[(size_t)n * 32 + c2] = __floats2half2_rn(vx, vy);
}

// ---- pull prop C=32: wave/node, quarter-waves split edges, 4-deep unroll ----
__global__ void k_prop32(const __half2* __restrict__ H2, const int* __restrict__ rec,
                         const int* __restrict__ rowptr, const float* __restrict__ dinv,
                         const float* __restrict__ bias, float* __restrict__ out, int N) {
  const int gid = blockIdx.x * blockDim.x + threadIdx.x;
  const int n = gid >> 6;
  if (n >= N) return;
  const int lane = threadIdx.x & 63;
  const int q = lane >> 4;
  const int c2 = lane & 15;
  const float di = dinv[n];
  const int beg = rowptr[n];
  const int end = rowptr[n + 1];
  float ax[4] = {0.f, 0.f, 0.f, 0.f}, ay[4] = {0.f, 0.f, 0.f, 0.f};
  if (q == 0) {
    float2 hv = __half22float2(H2[(size_t)n * 16 + c2]);  // self-loop term
    ax[0] = hv.x; ay[0] = hv.y;
  }
  for (int e = beg + q; e < end; e += 16) {
#pragma unroll
    for (int u = 0; u < 4; ++u) {
      int ee = e + 4 * u;
      bool ok = ee < end;
      int s = ok ? rec[ee] : 0;
      float2 hv = __half22float2(H2[(size_t)s * 16 + c2]);
      ax[u] += ok ? hv.x : 0.f;
      ay[u] += ok ? hv.y : 0.f;
    }
  }
  float vx = ax[0] + ax[1] + ax[2] + ax[3];
  float vy = ay[0] + ay[1] + ay[2] + ay[3];
  vx += __shfl_xor(vx, 16); vx += __shfl_xor(vx, 32);
  vy += __shfl_xor(vy, 16); vy += __shfl_xor(vy, 32);
  if (q) return;
  float2 bb = ((const float2*)bias)[c2];
  ((float2*)out)[(size_t)n * 16 + c2] =
      make_float2(fmaf(vx, di, bb.x), fmaf(vy, di, bb.y));
}

extern "C" void kernel_launch(void* const* d_in, const int* in_sizes, int n_in,
                              void* d_out, int out_size, void* d_ws, size_t ws_size,
                              hipStream_t stream) {
  (void)n_in; (void)out_size; (void)ws_size;
  const float* x = (const float*)d_in[0];
  const int* edges = (const int*)d_in[1];
  const float* W1 = (const float*)d_in[2];
  const float* b1 = (const float*)d_in[3];
  const float* W2 = (const float*)d_in[4];
  const float* b2 = (const float*)d_in[5];

  const int N = in_sizes[0] / 64;
  const int E = in_sizes[1] / 2;
  const int NCH = (E + CHUNK - 1) / CHUNK;        // 391 (<= 512)
  const int NBUCK = (N + BKN - 1) / BKN;          // 391 (<= 512)

  // workspace carve-up (256B aligned)
  char* ws = (char*)d_ws;
  size_t off = 0;
  auto carve = [&](size_t bytes) -> void* {
    void* p = ws + off;
    off = (off + bytes + 255) & ~(size_t)255;
    return p;
  };
  int* flag          = (int*)carve(4);
  int* cnt           = (int*)carve((size_t)N * 4);
  int* rowptr        = (int*)carve((size_t)(N + 1) * 4);
  int* gcur          = (int*)carve((size_t)N * 4);
  float* dinv        = (float*)carve((size_t)N * 4);
  int* partial       = (int*)carve(1024);
  int* histM         = (int*)carve((size_t)NCH * NBUCK * 4);
  unsigned int* raw  = (unsigned int*)carve((size_t)E * 4);
  int* rec           = (int*)carve((size_t)E * 4);
  __half* h1         = (__half*)carve((size_t)N * 64 * 2);
  __half* g1         = (__half*)carve((size_t)N * 64 * 2);
  __half* h2         = (__half*)carve((size_t)N * 32 * 2);

  const int nbN = (N + 255) / 256;
  const int NB = (N + 1023) / 1024;  // must be <= 256 (N <= 262144)

  hipMemsetAsync(cnt, 0, (size_t)N * 4, stream);
  hipMemsetAsync(flag, 1, 4, stream);  // 0x01010101 = truthy (int64 assumed)
  k_detect<<<4, 256, 0, stream>>>(edges, 2 * E, flag);
  k_histA<<<NCH, 256, 0, stream>>>(edges, E, cnt, histM, NBUCK, flag);
  k_scan1<<<NB, 256, 0, stream>>>(cnt, N, rowptr, partial);
  k_scan2<<<1, 256, 0, stream>>>(partial, NB);
  k_scan3<<<nbN, 256, 0, stream>>>(rowptr, partial, cnt, dinv, gcur, N, E);
  k_colscan<<<NBUCK, 256, 0, stream>>>(histM, rowptr, NCH, NBUCK);
  k_scatter<<<NCH, 256, 0, stream>>>(edges, E, histM, NBUCK, raw, flag);
  k_sort<<<NBUCK, 256, 0, stream>>>(raw, rowptr, rec, gcur, N);

  k_gemm<64, 64, false><<<(N + 15) / 16, 256, 0, stream>>>(x, W1, dinv, h1, N);
  k_prop64<<<(N + 3) / 4, 256, 0, stream>>>((const __half2*)h1, rec, rowptr, dinv,
                                            b1, g1, N);
  k_gemm<64, 32, true><<<(N + 31) / 32, 256, 0, stream>>>(g1, W2, dinv, h2, N);
  k_prop32<<<(N + 3) / 4, 256, 0, stream>>>((const __half2*)h2, rec, rowptr, dinv,
                                            b2, (float*)d_out, N);
}

// Round 8
// 183.168 us; speedup vs baseline: 6.0836x; 1.5046x over previous
//
#include <hip/hip_runtime.h>
#include <hip/hip_fp16.h>
#include <cstdint>
#include <cstddef>

// ---------------------------------------------------------------------------
// GCN 2-layer: out = GCNConv2( relu( GCNConv1(x) ) )
// Build — zero global atomics:
//   k_histA    : per-chunk LDS histogram over 256-node buckets -> histM
//   k_colscanA : per-bucket scan over chunks (chunk offsets) + bucket totals
//   k_bscan    : 1-block scan of bucket totals -> bbase[] (+ rowptr[N]=E)
//   k_scatter  : direct scatter via LDS cursors into bucket-grouped raw[]
//   k_sort     : per-bucket LDS node-histogram + scan -> rowptr, dinv (coalesced,
//                atomic-free) + LDS counting sort -> per-node CSR rec[]
// Compute:
//   k_gemm : Hs(fp16) = (X @ W) * dinv[row]  (norm folded into epilogue)
//   k_prop : out[n] = dinv[n]*(sum_e Hs[src] + Hs[n]) + bias  (pull; 8-lane
//            groups x float4 gathers: 8 edges per wave-instruction)
// Edge dtype (int32 vs int64) detected on-device via high words.
// ---------------------------------------------------------------------------

#define CHUNK 4096      // edges per partition block
#define BKN 256         // nodes per bucket
#define BKN_SHIFT 8
#define NCH_MAX 512     // max chunks (E <= 2.09M) / max buckets (N <= 131072)
#define SCAP2 5120      // LDS cap per bucket in k_sort (mean 4096, +16 sigma)

__global__ void k_detect(const int* __restrict__ e32, int twoE, int* __restrict__ flag) {
  int i = blockIdx.x * blockDim.x + threadIdx.x;
  if (i < 1024) {
    int idx = 2 * i + 1;  // odd int32 slots = high words if buffer is int64
    if (idx < twoE && e32[idx] != 0) atomicAnd(flag, 0);  // int32 data
  }
}

__device__ __forceinline__ int load_edge(const int* e32, int idx, int is64) {
  if (is64) return (int)((const long long*)e32)[idx];
  return e32[idx];
}

// ---- per-chunk bucket histogram (LDS atomics only, no global atomics) ----
__global__ void k_histA(const int* __restrict__ e32, int E, int* __restrict__ histM,
                        int NBUCK, const int* __restrict__ flag) {
  __shared__ int lh[NCH_MAX];
  const int c = blockIdx.x;
  const int t = threadIdx.x;
  for (int i = t; i < NBUCK; i += 256) lh[i] = 0;
  __syncthreads();
  const int is64 = *flag;
  const int beg = c * CHUNK;
  const int n = min(CHUNK, E - beg);
  for (int i = t; i < n; i += 256) {
    int d = load_edge(e32, E + beg + i, is64);
    atomicAdd(&lh[d >> BKN_SHIFT], 1);  // LDS atomic: on-CU, cheap
  }
  __syncthreads();
  for (int i = t; i < NBUCK; i += 256) histM[(size_t)c * NBUCK + i] = lh[i];
}

// inclusive Hillis-Steele over 512 LDS slots with 256 threads
__device__ __forceinline__ void block_scan512(int* sh, int t) {
  for (int off = 1; off < 512; off <<= 1) {
    int i0 = t, i1 = t + 256;
    int v0 = sh[i0] + ((i0 >= off) ? sh[i0 - off] : 0);
    int v1 = sh[i1] + ((i1 >= off) ? sh[i1 - off] : 0);
    __syncthreads();
    sh[i0] = v0;
    sh[i1] = v1;
    __syncthreads();
  }
}

// ---- per-bucket scan over chunks: histM -> within-bucket chunk offsets ----
__global__ void k_colscanA(int* __restrict__ histM, int* __restrict__ btot,
                           int NCH, int NBUCK) {
  __shared__ int sh[NCH_MAX];
  const int b = blockIdx.x;
  const int t = threadIdx.x;
  for (int i = t; i < NCH_MAX; i += 256)
    sh[i] = (i < NCH) ? histM[(size_t)i * NBUCK + b] : 0;
  __syncthreads();
  block_scan512(sh, t);  // inclusive
  for (int i = t; i < NCH; i += 256)
    histM[(size_t)i * NBUCK + b] = (i == 0) ? 0 : sh[i - 1];  // exclusive, no base
  if (t == 0) btot[b] = sh[NCH_MAX - 1];  // bucket total (tail slots are zero)
}

// ---- single-block scan of bucket totals -> bucket bases ----
__global__ void k_bscan(const int* __restrict__ btot, int* __restrict__ bbase,
                        int* __restrict__ rowptr, int NBUCK, int N, int E) {
  __shared__ int sh[NCH_MAX];
  const int t = threadIdx.x;
  sh[t] = (t < NBUCK) ? btot[t] : 0;
  sh[t + 256] = (t + 256 < NBUCK) ? btot[t + 256] : 0;
  __syncthreads();
  block_scan512(sh, t);  // inclusive
  for (int i = t; i < NBUCK; i += 256) bbase[i] = (i == 0) ? 0 : sh[i - 1];
  if (t == 0) { bbase[NBUCK] = E; rowptr[N] = E; }
}

// ---- direct scatter: LDS cursor per bucket, one global write per edge ----
__global__ void k_scatter(const int* __restrict__ e32, int E, const int* __restrict__ histM,
                          const int* __restrict__ bbase, int NBUCK,
                          unsigned int* __restrict__ raw, const int* __restrict__ flag) {
  __shared__ int lcur[NCH_MAX];
  const int c = blockIdx.x;
  const int t = threadIdx.x;
  for (int i = t; i < NBUCK; i += 256)
    lcur[i] = histM[(size_t)c * NBUCK + i] + bbase[i];
  __syncthreads();
  const int is64 = *flag;
  const int beg = c * CHUNK;
  const int cnt = min(CHUNK, E - beg);
  for (int i = t; i < cnt; i += 256) {
    int s = load_edge(e32, beg + i, is64);
    int d = load_edge(e32, E + beg + i, is64);
    int pos = atomicAdd(&lcur[d >> BKN_SHIFT], 1);
    raw[pos] = ((unsigned int)(d & (BKN - 1)) << 23) | (unsigned int)s;
  }
}

// ---- per-bucket: node histogram + scan -> rowptr/dinv; counting sort -> rec ----
__global__ void k_sort(const unsigned int* __restrict__ raw, const int* __restrict__ bbase,
                       int* __restrict__ rec, int* __restrict__ rowptr,
                       float* __restrict__ dinv, int N) {
  __shared__ int srec[SCAP2];
  __shared__ int sh[BKN];
  const int b = blockIdx.x;
  const int t = threadIdx.x;
  const int nodebase = b << BKN_SHIFT;
  const int base = bbase[b];
  const int end = bbase[b + 1];
  const int count = end - base;
  sh[t] = 0;
  __syncthreads();
  for (int i = t; i < count; i += 256) atomicAdd(&sh[raw[base + i] >> 23], 1);
  __syncthreads();
  const int deg = sh[t];  // in-degree of node nodebase+t
  // inclusive scan of sh
  for (int off = 1; off < 256; off <<= 1) {
    int add = (t >= off) ? sh[t - off] : 0;
    __syncthreads();
    sh[t] += add;
    __syncthreads();
  }
  const int excl = sh[t] - deg;
  const int n = nodebase + t;
  if (n < N) {
    rowptr[n] = base + excl;                   // coalesced, atomic-free
    dinv[n] = rsqrtf((float)deg + 1.0f);       // +1 = self-loop
  }
  __syncthreads();
  sh[t] = excl;  // cursors (local)
  __syncthreads();
  if (count <= SCAP2) {
    for (int i = t; i < count; i += 256) {
      unsigned int r = raw[base + i];
      int pos = atomicAdd(&sh[r >> 23], 1);
      srec[pos] = (int)(r & 0x7FFFFFu);
    }
    __syncthreads();
    for (int i = t; i < count; i += 256) rec[base + i] = srec[i];
  } else {  // statistically unreachable fallback: direct global placement
    for (int i = t; i < count; i += 256) {
      unsigned int r = raw[base + i];
      int pos = atomicAdd(&sh[r >> 23], 1);
      rec[base + pos] = (int)(r & 0x7FFFFFu);
    }
  }
}

// ---- dense transform Hs[N][COUT] = (X[N][CIN] @ W) * dinv[row], fp16 out ----
template <int CIN, int COUT, bool IN16>
__global__ void k_gemm(const void* __restrict__ Xv, const float* __restrict__ W,
                       const float* __restrict__ dinv, __half* __restrict__ H, int N) {
  constexpr int Q = COUT / 4;
  constexpr int NODES = 256 / Q;
  __shared__ float4 Ws[CIN * Q];
  __shared__ float Xs[NODES][CIN + 1];
  const int t = threadIdx.x;
  const int nodebase = blockIdx.x * NODES;

  const float4* W4 = (const float4*)W;
#pragma unroll
  for (int i = t; i < CIN * Q; i += 256) Ws[i] = W4[i];

  if (IN16) {
    const __half2* X2 = (const __half2*)Xv;
#pragma unroll
    for (int i = t; i < NODES * (CIN / 2); i += 256) {
      int r = i / (CIN / 2);
      int k2 = i % (CIN / 2);
      int gr = nodebase + r;
      if (gr > N - 1) gr = N - 1;
      float2 f = __half22float2(X2[(size_t)gr * (CIN / 2) + k2]);
      Xs[r][k2 * 2 + 0] = f.x;
      Xs[r][k2 * 2 + 1] = f.y;
    }
  } else {
    const float4* X4 = (const float4*)Xv;
#pragma unroll
    for (int i = t; i < NODES * (CIN / 4); i += 256) {
      int r = i / (CIN / 4);
      int k4 = i % (CIN / 4);
      int gr = nodebase + r;
      if (gr > N - 1) gr = N - 1;
      float4 v = X4[(size_t)gr * (CIN / 4) + k4];
      Xs[r][k4 * 4 + 0] = v.x;
      Xs[r][k4 * 4 + 1] = v.y;
      Xs[r][k4 * 4 + 2] = v.z;
      Xs[r][k4 * 4 + 3] = v.w;
    }
  }
  __syncthreads();

  const int q = t % Q;
  const int nl = t / Q;
  const int n = nodebase + nl;
  float4 acc = make_float4(0.f, 0.f, 0.f, 0.f);
#pragma unroll 4
  for (int k = 0; k < CIN; ++k) {
    float xv = Xs[nl][k];
    float4 wv = Ws[k * Q + q];
    acc.x = fmaf(xv, wv.x, acc.x);
    acc.y = fmaf(xv, wv.y, acc.y);
    acc.z = fmaf(xv, wv.z, acc.z);
    acc.w = fmaf(xv, wv.w, acc.w);
  }
  if (n < N) {
    float dn = dinv[n];  // fold symmetric norm into stored features
    __half2* H2 = (__half2*)H;
    H2[(size_t)n * (COUT / 2) + 2 * q + 0] = __floats2half2_rn(acc.x * dn, acc.y * dn);
    H2[(size_t)n * (COUT / 2) + 2 * q + 1] = __floats2half2_rn(acc.z * dn, acc.w * dn);
  }
}

// accumulate a float4 (= 8 fp16 channels) into 4 float2 accumulators, predicated
__device__ __forceinline__ void acc_row(float4 hv, bool ok, float2& a0, float2& a1,
                                        float2& a2, float2& a3) {
  union { float f; __half2 h; } c0, c1, c2, c3;
  c0.f = hv.x; c1.f = hv.y; c2.f = hv.z; c3.f = hv.w;
  float2 f0 = __half22float2(c0.h), f1 = __half22float2(c1.h);
  float2 f2 = __half22float2(c2.h), f3 = __half22float2(c3.h);
  a0.x += ok ? f0.x : 0.f; a0.y += ok ? f0.y : 0.f;
  a1.x += ok ? f1.x : 0.f; a1.y += ok ? f1.y : 0.f;
  a2.x += ok ? f2.x : 0.f; a2.y += ok ? f2.y : 0.f;
  a3.x += ok ? f3.x : 0.f; a3.y += ok ? f3.y : 0.f;
}

#define RED2(v, m) { v.x += __shfl_xor(v.x, m); v.y += __shfl_xor(v.y, m); }

// ---- pull prop C=64: wave/node, 8-lane groups x float4 (8 edges/instr) ----
__global__ void k_prop64(const __half2* __restrict__ H2, const int* __restrict__ rec,
                         const int* __restrict__ rowptr, const float* __restrict__ dinv,
                         const float* __restrict__ bias, __half* __restrict__ out, int N) {
  const int gid = blockIdx.x * blockDim.x + threadIdx.x;
  const int n = gid >> 6;
  if (n >= N) return;
  const int lane = threadIdx.x & 63;
  const int g = lane >> 3;   // edge group 0..7
  const int l8 = lane & 7;   // float4 index within row (8 channels)
  const float di = dinv[n];
  const int beg = rowptr[n];
  const int end = rowptr[n + 1];
  const float4* H4 = (const float4*)H2;
  float2 a0 = {0.f, 0.f}, a1 = {0.f, 0.f}, a2 = {0.f, 0.f}, a3 = {0.f, 0.f};
  if (g == 0) acc_row(H4[(size_t)n * 8 + l8], true, a0, a1, a2, a3);  // self-loop
  for (int e = beg + g; e < end; e += 32) {
#pragma unroll
    for (int u = 0; u < 4; ++u) {
      int ee = e + 8 * u;
      bool ok = ee < end;
      int s = ok ? rec[ee] : 0;
      acc_row(H4[(size_t)s * 8 + l8], ok, a0, a1, a2, a3);
    }
  }
  RED2(a0, 8)  RED2(a1, 8)  RED2(a2, 8)  RED2(a3, 8)
  RED2(a0, 16) RED2(a1, 16) RED2(a2, 16) RED2(a3, 16)
  RED2(a0, 32) RED2(a1, 32) RED2(a2, 32) RED2(a3, 32)
  if (g) return;
  const float4* B4 = (const float4*)bias;
  float4 b0 = B4[l8 * 2 + 0], b1 = B4[l8 * 2 + 1];
  union { float4 f4; __half2 h2[4]; } st;
  st.h2[0] = __floats2half2_rn(fmaxf(fmaf(a0.x, di, b0.x), 0.f),
                               fmaxf(fmaf(a0.y, di, b0.y), 0.f));
  st.h2[1] = __floats2half2_rn(fmaxf(fmaf(a1.x, di, b0.z), 0.f),
                               fmaxf(fmaf(a1.y, di, b0.w), 0.f));
  st.h2[2] = __floats2half2_rn(fmaxf(fmaf(a2.x, di, b1.x), 0.f),
                               fmaxf(fmaf(a2.y, di, b1.y), 0.f));
  st.h2[3] = __floats2half2_rn(fmaxf(fmaf(a3.x, di, b1.z), 0.f),
                               fmaxf(fmaf(a3.y, di, b1.w), 0.f));
  ((float4*)out)[(size_t)n * 8 + l8] = st.f4;
}

// ---- pull prop C=32: wave/node, 4-lane groups x float4 (16 edges/instr) ----
__global__ void k_prop32(const __half2* __restrict__ H2, const int* __restrict__ rec,
                         const int* __restrict__ rowptr, const float* __restrict__ dinv,
                         const float* __restrict__ bias, float* __restrict__ out, int N) {
  const int gid = blockIdx.x * blockDim.x + threadIdx.x;
  const int n = gid >> 6;
  if (n >= N) return;
  const int lane = threadIdx.x & 63;
  const int g = lane >> 2;   // edge group 0..15
  const int l4 = lane & 3;   // float4 index within row (8 channels)
  const float di = dinv[n];
  const int beg = rowptr[n];
  const int end = rowptr[n + 1];
  const float4* H4 = (const float4*)H2;
  float2 a0 = {0.f, 0.f}, a1 = {0.f, 0.f}, a2 = {0.f, 0.f}, a3 = {0.f, 0.f};
  if (g == 0) acc_row(H4[(size_t)n * 4 + l4], true, a0, a1, a2, a3);  // self-loop
  for (int e = beg + g; e < end; e += 32) {
#pragma unroll
    for (int u = 0; u < 2; ++u) {
      int ee = e + 16 * u;
      bool ok = ee < end;
      int s = ok ? rec[ee] : 0;
      acc_row(H4[(size_t)s * 4 + l4], ok, a0, a1, a2, a3);
    }
  }
  RED2(a0, 4)  RED2(a1, 4)  RED2(a2, 4)  RED2(a3, 4)
  RED2(a0, 8)  RED2(a1, 8)  RED2(a2, 8)  RED2(a3, 8)
  RED2(a0, 16) RED2(a1, 16) RED2(a2, 16) RED2(a3, 16)
  RED2(a0, 32) RED2(a1, 32) RED2(a2, 32) RED2(a3, 32)
  if (g) return;
  const float4* B4 = (const float4*)bias;
  float4 b0 = B4[l4 * 2 + 0], b1 = B4[l4 * 2 + 1];
  ((float4*)out)[(size_t)n * 8 + l4 * 2 + 0] =
      make_float4(fmaf(a0.x, di, b0.x), fmaf(a0.y, di, b0.y),
                  fmaf(a1.x, di, b0.z), fmaf(a1.y, di, b0.w));
  ((float4*)out)[(size_t)n * 8 + l4 * 2 + 1] =
      make_float4(fmaf(a2.x, di, b1.x), fmaf(a2.y, di, b1.y),
                  fmaf(a3.x, di, b1.z), fmaf(a3.y, di, b1.w));
}

extern "C" void kernel_launch(void* const* d_in, const int* in_sizes, int n_in,
                              void* d_out, int out_size, void* d_ws, size_t ws_size,
                              hipStream_t stream) {
  (void)n_in; (void)out_size; (void)ws_size;
  const float* x = (const float*)d_in[0];
  const int* edges = (const int*)d_in[1];
  const float* W1 = (const float*)d_in[2];
  const float* b1 = (const float*)d_in[3];
  const float* W2 = (const float*)d_in[4];
  const float* b2 = (const float*)d_in[5];

  const int N = in_sizes[0] / 64;
  const int E = in_sizes[1] / 2;
  const int NCH = (E + CHUNK - 1) / CHUNK;        // 391 (<= 512)
  const int NBUCK = (N + BKN - 1) / BKN;          // 391 (<= 512)

  // workspace carve-up (256B aligned)
  char* ws = (char*)d_ws;
  size_t off = 0;
  auto carve = [&](size_t bytes) -> void* {
    void* p = ws + off;
    off = (off + bytes + 255) & ~(size_t)255;
    return p;
  };
  int* flag          = (int*)carve(4);
  int* rowptr        = (int*)carve((size_t)(N + 1) * 4);
  float* dinv        = (float*)carve((size_t)N * 4);
  int* btot          = (int*)carve((size_t)NBUCK * 4);
  int* bbase         = (int*)carve((size_t)(NBUCK + 1) * 4);
  int* histM         = (int*)carve((size_t)NCH * NBUCK * 4);
  unsigned int* raw  = (unsigned int*)carve((size_t)E * 4);
  int* rec           = (int*)carve((size_t)E * 4);
  __half* h1         = (__half*)carve((size_t)N * 64 * 2);
  __half* g1         = (__half*)carve((size_t)N * 64 * 2);
  __half* h2         = (__half*)carve((size_t)N * 32 * 2);

  hipMemsetAsync(flag, 1, 4, stream);  // 0x01010101 = truthy (int64 assumed)
  k_detect<<<4, 256, 0, stream>>>(edges, 2 * E, flag);
  k_histA<<<NCH, 256, 0, stream>>>(edges, E, histM, NBUCK, flag);
  k_colscanA<<<NBUCK, 256, 0, stream>>>(histM, btot, NCH, NBUCK);
  k_bscan<<<1, 256, 0, stream>>>(btot, bbase, rowptr, NBUCK, N, E);
  k_scatter<<<NCH, 256, 0, stream>>>(edges, E, histM, bbase, NBUCK, raw, flag);
  k_sort<<<NBUCK, 256, 0, stream>>>(raw, bbase, rec, rowptr, dinv, N);

  k_gemm<64, 64, false><<<(N + 15) / 16, 256, 0, stream>>>(x, W1, dinv, h1, N);
  k_prop64<<<(N + 3) / 4, 256, 0, stream>>>((const __half2*)h1, rec, rowptr, dinv,
                                            b1, g1, N);
  k_gemm<64, 32, true><<<(N + 31) / 32, 256, 0, stream>>>(g1, W2, dinv, h2, N);
  k_prop32<<<(N + 3) / 4, 256, 0, stream>>>((const __half2*)h2, rec, rowptr, dinv,
                                            b2, (float*)d_out, N);
}

// Round 9
// 155.956 us; speedup vs baseline: 7.1450x; 1.1745x over previous
//
#include <hip/hip_runtime.h>
#include <hip/hip_fp16.h>
#include <cstdint>
#include <cstddef>

// ---------------------------------------------------------------------------
// GCN 2-layer: out = GCNConv2( relu( GCNConv1(x) ) )
// Build — zero global atomics, zero extra passes:
//   k_histA    : per-chunk LDS histogram over 256-node buckets -> histM
//   k_colscanA : per-bucket scan over chunks (chunk offsets) + bucket totals
//   k_bscan    : 1-block scan of bucket totals -> bbase[]; zeroes row N of
//                feature buffers (zero-row for predication-free gathers)
//   k_scatter  : direct scatter via LDS cursors into bucket-grouped raw[]
//   k_sort     : per-bucket LDS node-histogram + scan -> rowptr/dinv +
//                LDS counting sort -> per-node CSR rec[]
// Compute:
//   k_gemm : Hs(fp16) = (X @ W) * dinv[row]  (norm folded into epilogue)
//   k_prop : out[n] = dinv[n]*(sum_e Hs[src] + Hs[n]) + bias
//            (pull; 8-lane groups x float4; tail slots gather zero-row N ->
//             single cndmask per edge, unconditional accumulate)
// Edge dtype (int32 vs int64) detected per-block via wave-0 ballot on the
// odd 32-bit words of the first 64 edges (int64 node ids < 2^31 -> all 0).
// ---------------------------------------------------------------------------

#define CHUNK 4096      // edges per partition block
#define BKN 256         // nodes per bucket
#define BKN_SHIFT 8
#define NCH_MAX 512     // max chunks (E <= 2.09M) / max buckets (N <= 131072)
#define SCAP2 5120      // LDS cap per bucket in k_sort (mean 4096, +16 sigma)

__device__ __forceinline__ int load_edge(const int* e32, int idx, int is64) {
  if (is64) return (int)((const long long*)e32)[idx];
  return e32[idx];
}

// wave-0 ballot over odd words of first 64 edges; result via LDS to all waves.
__device__ __forceinline__ int detect_is64_block(const int* e32, int* s_tmp) {
  const int t = threadIdx.x;
  if (t < 64) {
    int v = e32[2 * t + 1];
    unsigned long long b = __ballot(v != 0);
    if (t == 0) *s_tmp = (b == 0ULL);  // all-zero high words -> int64
  }
  __syncthreads();
  return *s_tmp;
}

// ---- per-chunk bucket histogram (LDS atomics only, no global atomics) ----
__global__ void k_histA(const int* __restrict__ e32, int E, int* __restrict__ histM,
                        int NBUCK) {
  __shared__ int lh[NCH_MAX];
  __shared__ int s_is64;
  const int c = blockIdx.x;
  const int t = threadIdx.x;
  const int is64 = detect_is64_block(e32, &s_is64);
  for (int i = t; i < NBUCK; i += 256) lh[i] = 0;
  __syncthreads();
  const int beg = c * CHUNK;
  const int n = min(CHUNK, E - beg);
  for (int i = t; i < n; i += 256) {
    int d = load_edge(e32, E + beg + i, is64);
    atomicAdd(&lh[d >> BKN_SHIFT], 1);  // LDS atomic: on-CU, cheap
  }
  __syncthreads();
  for (int i = t; i < NBUCK; i += 256) histM[(size_t)c * NBUCK + i] = lh[i];
}

// inclusive Hillis-Steele over 512 LDS slots with 256 threads
__device__ __forceinline__ void block_scan512(int* sh, int t) {
  for (int off = 1; off < 512; off <<= 1) {
    int i0 = t, i1 = t + 256;
    int v0 = sh[i0] + ((i0 >= off) ? sh[i0 - off] : 0);
    int v1 = sh[i1] + ((i1 >= off) ? sh[i1 - off] : 0);
    __syncthreads();
    sh[i0] = v0;
    sh[i1] = v1;
    __syncthreads();
  }
}

// ---- per-bucket scan over chunks: histM -> within-bucket chunk offsets ----
__global__ void k_colscanA(int* __restrict__ histM, int* __restrict__ btot,
                           int NCH, int NBUCK) {
  __shared__ int sh[NCH_MAX];
  const int b = blockIdx.x;
  const int t = threadIdx.x;
  for (int i = t; i < NCH_MAX; i += 256)
    sh[i] = (i < NCH) ? histM[(size_t)i * NBUCK + b] : 0;
  __syncthreads();
  block_scan512(sh, t);  // inclusive
  for (int i = t; i < NCH; i += 256)
    histM[(size_t)i * NBUCK + b] = (i == 0) ? 0 : sh[i - 1];  // exclusive, no base
  if (t == 0) btot[b] = sh[NCH_MAX - 1];  // bucket total (tail slots are zero)
}

// ---- single-block: scan bucket totals -> bases; zero the zero-rows ----
__global__ void k_bscan(const int* __restrict__ btot, int* __restrict__ bbase,
                        int* __restrict__ rowptr, __half* __restrict__ h1,
                        __half* __restrict__ g1, __half* __restrict__ h2,
                        int NBUCK, int N, int E) {
  __shared__ int sh[NCH_MAX];
  const int t = threadIdx.x;
  sh[t] = (t < NBUCK) ? btot[t] : 0;
  sh[t + 256] = (t + 256 < NBUCK) ? btot[t + 256] : 0;
  __syncthreads();
  block_scan512(sh, t);  // inclusive
  for (int i = t; i < NBUCK; i += 256) bbase[i] = (i == 0) ? 0 : sh[i - 1];
  if (t == 0) { bbase[NBUCK] = E; rowptr[N] = E; }
  // zero-row at index N (gather target for tail slots)
  if (t < 64) {
    h1[(size_t)N * 64 + t] = __float2half(0.f);
    g1[(size_t)N * 64 + t] = __float2half(0.f);
    if (t < 32) h2[(size_t)N * 32 + t] = __float2half(0.f);
  }
}

// ---- direct scatter: LDS cursor per bucket, one global write per edge ----
__global__ void k_scatter(const int* __restrict__ e32, int E, const int* __restrict__ histM,
                          const int* __restrict__ bbase, int NBUCK,
                          unsigned int* __restrict__ raw) {
  __shared__ int lcur[NCH_MAX];
  __shared__ int s_is64;
  const int c = blockIdx.x;
  const int t = threadIdx.x;
  const int is64 = detect_is64_block(e32, &s_is64);
  for (int i = t; i < NBUCK; i += 256)
    lcur[i] = histM[(size_t)c * NBUCK + i] + bbase[i];
  __syncthreads();
  const int beg = c * CHUNK;
  const int cnt = min(CHUNK, E - beg);
  for (int i = t; i < cnt; i += 256) {
    int s = load_edge(e32, beg + i, is64);
    int d = load_edge(e32, E + beg + i, is64);
    int pos = atomicAdd(&lcur[d >> BKN_SHIFT], 1);
    raw[pos] = ((unsigned int)(d & (BKN - 1)) << 23) | (unsigned int)s;
  }
}

// ---- per-bucket: node histogram + scan -> rowptr/dinv; counting sort -> rec ----
__global__ void k_sort(const unsigned int* __restrict__ raw, const int* __restrict__ bbase,
                       int* __restrict__ rec, int* __restrict__ rowptr,
                       float* __restrict__ dinv, int N) {
  __shared__ int srec[SCAP2];
  __shared__ int sh[BKN];
  const int b = blockIdx.x;
  const int t = threadIdx.x;
  const int nodebase = b << BKN_SHIFT;
  const int base = bbase[b];
  const int end = bbase[b + 1];
  const int count = end - base;
  sh[t] = 0;
  __syncthreads();
  for (int i = t; i < count; i += 256) atomicAdd(&sh[raw[base + i] >> 23], 1);
  __syncthreads();
  const int deg = sh[t];  // in-degree of node nodebase+t
  // inclusive scan of sh
  for (int off = 1; off < 256; off <<= 1) {
    int add = (t >= off) ? sh[t - off] : 0;
    __syncthreads();
    sh[t] += add;
    __syncthreads();
  }
  const int excl = sh[t] - deg;
  const int n = nodebase + t;
  if (n < N) {
    rowptr[n] = base + excl;                   // coalesced, atomic-free
    dinv[n] = rsqrtf((float)deg + 1.0f);       // +1 = self-loop
  }
  __syncthreads();
  sh[t] = excl;  // cursors (local)
  __syncthreads();
  if (count <= SCAP2) {
    for (int i = t; i < count; i += 256) {
      unsigned int r = raw[base + i];
      int pos = atomicAdd(&sh[r >> 23], 1);
      srec[pos] = (int)(r & 0x7FFFFFu);
    }
    __syncthreads();
    for (int i = t; i < count; i += 256) rec[base + i] = srec[i];
  } else {  // statistically unreachable fallback: direct global placement
    for (int i = t; i < count; i += 256) {
      unsigned int r = raw[base + i];
      int pos = atomicAdd(&sh[r >> 23], 1);
      rec[base + pos] = (int)(r & 0x7FFFFFu);
    }
  }
}

// ---- dense transform Hs[N][COUT] = (X[N][CIN] @ W) * dinv[row], fp16 out ----
template <int CIN, int COUT, bool IN16>
__global__ void k_gemm(const void* __restrict__ Xv, const float* __restrict__ W,
                       const float* __restrict__ dinv, __half* __restrict__ H, int N) {
  constexpr int Q = COUT / 4;
  constexpr int NODES = 256 / Q;
  __shared__ float4 Ws[CIN * Q];
  __shared__ float Xs[NODES][CIN + 1];
  const int t = threadIdx.x;
  const int nodebase = blockIdx.x * NODES;

  const float4* W4 = (const float4*)W;
#pragma unroll
  for (int i = t; i < CIN * Q; i += 256) Ws[i] = W4[i];

  if (IN16) {
    const __half2* X2 = (const __half2*)Xv;
#pragma unroll
    for (int i = t; i < NODES * (CIN / 2); i += 256) {
      int r = i / (CIN / 2);
      int k2 = i % (CIN / 2);
      int gr = nodebase + r;
      if (gr > N - 1) gr = N - 1;
      float2 f = __half22float2(X2[(size_t)gr * (CIN / 2) + k2]);
      Xs[r][k2 * 2 + 0] = f.x;
      Xs[r][k2 * 2 + 1] = f.y;
    }
  } else {
    const float4* X4 = (const float4*)Xv;
#pragma unroll
    for (int i = t; i < NODES * (CIN / 4); i += 256) {
      int r = i / (CIN / 4);
      int k4 = i % (CIN / 4);
      int gr = nodebase + r;
      if (gr > N - 1) gr = N - 1;
      float4 v = X4[(size_t)gr * (CIN / 4) + k4];
      Xs[r][k4 * 4 + 0] = v.x;
      Xs[r][k4 * 4 + 1] = v.y;
      Xs[r][k4 * 4 + 2] = v.z;
      Xs[r][k4 * 4 + 3] = v.w;
    }
  }
  __syncthreads();

  const int q = t % Q;
  const int nl = t / Q;
  const int n = nodebase + nl;
  float4 acc = make_float4(0.f, 0.f, 0.f, 0.f);
#pragma unroll 4
  for (int k = 0; k < CIN; ++k) {
    float xv = Xs[nl][k];
    float4 wv = Ws[k * Q + q];
    acc.x = fmaf(xv, wv.x, acc.x);
    acc.y = fmaf(xv, wv.y, acc.y);
    acc.z = fmaf(xv, wv.z, acc.z);
    acc.w = fmaf(xv, wv.w, acc.w);
  }
  if (n < N) {
    float dn = dinv[n];  // fold symmetric norm into stored features
    __half2* H2 = (__half2*)H;
    H2[(size_t)n * (COUT / 2) + 2 * q + 0] = __floats2half2_rn(acc.x * dn, acc.y * dn);
    H2[(size_t)n * (COUT / 2) + 2 * q + 1] = __floats2half2_rn(acc.z * dn, acc.w * dn);
  }
}

// accumulate a float4 (= 8 fp16 channels) into 4 float2 accumulators
__device__ __forceinline__ void acc_row(float4 hv, float2& a0, float2& a1,
                                        float2& a2, float2& a3) {
  union { float f; __half2 h; } c0, c1, c2, c3;
  c0.f = hv.x; c1.f = hv.y; c2.f = hv.z; c3.f = hv.w;
  float2 f0 = __half22float2(c0.h), f1 = __half22float2(c1.h);
  float2 f2 = __half22float2(c2.h), f3 = __half22float2(c3.h);
  a0.x += f0.x; a0.y += f0.y;
  a1.x += f1.x; a1.y += f1.y;
  a2.x += f2.x; a2.y += f2.y;
  a3.x += f3.x; a3.y += f3.y;
}

#define RED2(v, m) { v.x += __shfl_xor(v.x, m); v.y += __shfl_xor(v.y, m); }

// ---- pull prop C=64: wave/node, 8-lane groups x float4 (8 edges/instr) ----
// Tail slots select the zero-row N: one cndmask/edge, unconditional adds.
__global__ void k_prop64(const __half2* __restrict__ H2, const int* __restrict__ rec,
                         const int* __restrict__ rowptr, const float* __restrict__ dinv,
                         const float* __restrict__ bias, __half* __restrict__ out, int N) {
  const int gid = blockIdx.x * blockDim.x + threadIdx.x;
  const int n = gid >> 6;
  if (n >= N) return;
  const int lane = threadIdx.x & 63;
  const int g = lane >> 3;   // edge group 0..7
  const int l8 = lane & 7;   // float4 index within row (8 channels)
  const float di = dinv[n];
  const int beg = rowptr[n];
  const int end = rowptr[n + 1];
  const float4* H4 = (const float4*)H2;
  float2 a0 = {0.f, 0.f}, a1 = {0.f, 0.f}, a2 = {0.f, 0.f}, a3 = {0.f, 0.f};
  acc_row(H4[(size_t)(g == 0 ? n : N) * 8 + l8], a0, a1, a2, a3);  // self-loop
  for (int e = beg + g; e < end; e += 32) {
#pragma unroll
    for (int u = 0; u < 4; ++u) {
      int ee = e + 8 * u;
      int sv = rec[ee];                  // in-bounds: rec has +64 slack
      int s = (ee < end) ? sv : N;       // zero-row for tail slots
      acc_row(H4[(size_t)s * 8 + l8], a0, a1, a2, a3);
    }
  }
  RED2(a0, 8)  RED2(a1, 8)  RED2(a2, 8)  RED2(a3, 8)
  RED2(a0, 16) RED2(a1, 16) RED2(a2, 16) RED2(a3, 16)
  RED2(a0, 32) RED2(a1, 32) RED2(a2, 32) RED2(a3, 32)
  if (g) return;
  const float4* B4 = (const float4*)bias;
  float4 b0 = B4[l8 * 2 + 0], b1 = B4[l8 * 2 + 1];
  union { float4 f4; __half2 h2[4]; } st;
  st.h2[0] = __floats2half2_rn(fmaxf(fmaf(a0.x, di, b0.x), 0.f),
                               fmaxf(fmaf(a0.y, di, b0.y), 0.f));
  st.h2[1] = __floats2half2_rn(fmaxf(fmaf(a1.x, di, b0.z), 0.f),
                               fmaxf(fmaf(a1.y, di, b0.w), 0.f));
  st.h2[2] = __floats2half2_rn(fmaxf(fmaf(a2.x, di, b1.x), 0.f),
                               fmaxf(fmaf(a2.y, di, b1.y), 0.f));
  st.h2[3] = __floats2half2_rn(fmaxf(fmaf(a3.x, di, b1.z), 0.f),
                               fmaxf(fmaf(a3.y, di, b1.w), 0.f));
  ((float4*)out)[(size_t)n * 8 + l8] = st.f4;
}

// ---- pull prop C=32: wave/node, 4-lane groups x float4 (16 edges/instr) ----
__global__ void k_prop32(const __half2* __restrict__ H2, const int* __restrict__ rec,
                         const int* __restrict__ rowptr, const float* __restrict__ dinv,
                         const float* __restrict__ bias, float* __restrict__ out, int N) {
  const int gid = blockIdx.x * blockDim.x + threadIdx.x;
  const int n = gid >> 6;
  if (n >= N) return;
  const int lane = threadIdx.x & 63;
  const int g = lane >> 2;   // edge group 0..15
  const int l4 = lane & 3;   // float4 index within row (8 channels)
  const float di = dinv[n];
  const int beg = rowptr[n];
  const int end = rowptr[n + 1];
  const float4* H4 = (const float4*)H2;
  float2 a0 = {0.f, 0.f}, a1 = {0.f, 0.f}, a2 = {0.f, 0.f}, a3 = {0.f, 0.f};
  acc_row(H4[(size_t)(g == 0 ? n : N) * 4 + l4], a0, a1, a2, a3);  // self-loop
  for (int e = beg + g; e < end; e += 32) {
#pragma unroll
    for (int u = 0; u < 2; ++u) {
      int ee = e + 16 * u;
      int sv = rec[ee];                  // in-bounds: rec has +64 slack
      int s = (ee < end) ? sv : N;       // zero-row for tail slots
      acc_row(H4[(size_t)s * 4 + l4], a0, a1, a2, a3);
    }
  }
  RED2(a0, 4)  RED2(a1, 4)  RED2(a2, 4)  RED2(a3, 4)
  RED2(a0, 8)  RED2(a1, 8)  RED2(a2, 8)  RED2(a3, 8)
  RED2(a0, 16) RED2(a1, 16) RED2(a2, 16) RED2(a3, 16)
  RED2(a0, 32) RED2(a1, 32) RED2(a2, 32) RED2(a3, 32)
  if (g) return;
  const float4* B4 = (const float4*)bias;
  float4 b0 = B4[l4 * 2 + 0], b1 = B4[l4 * 2 + 1];
  ((float4*)out)[(size_t)n * 8 + l4 * 2 + 0] =
      make_float4(fmaf(a0.x, di, b0.x), fmaf(a0.y, di, b0.y),
                  fmaf(a1.x, di, b0.z), fmaf(a1.y, di, b0.w));
  ((float4*)out)[(size_t)n * 8 + l4 * 2 + 1] =
      make_float4(fmaf(a2.x, di, b1.x), fmaf(a2.y, di, b1.y),
                  fmaf(a3.x, di, b1.z), fmaf(a3.y, di, b1.w));
}

extern "C" void kernel_launch(void* const* d_in, const int* in_sizes, int n_in,
                              void* d_out, int out_size, void* d_ws, size_t ws_size,
                              hipStream_t stream) {
  (void)n_in; (void)out_size; (void)ws_size;
  const float* x = (const float*)d_in[0];
  const int* edges = (const int*)d_in[1];
  const float* W1 = (const float*)d_in[2];
  const float* b1 = (const float*)d_in[3];
  const float* W2 = (const float*)d_in[4];
  const float* b2 = (const float*)d_in[5];

  const int N = in_sizes[0] / 64;
  const int E = in_sizes[1] / 2;
  const int NCH = (E + CHUNK - 1) / CHUNK;        // 391 (<= 512)
  const int NBUCK = (N + BKN - 1) / BKN;          // 391 (<= 512)

  // workspace carve-up (256B aligned)
  char* ws = (char*)d_ws;
  size_t off = 0;
  auto carve = [&](size_t bytes) -> void* {
    void* p = ws + off;
    off = (off + bytes + 255) & ~(size_t)255;
    return p;
  };
  int* rowptr        = (int*)carve((size_t)(N + 1) * 4);
  float* dinv        = (float*)carve((size_t)N * 4);
  int* btot          = (int*)carve((size_t)NBUCK * 4);
  int* bbase         = (int*)carve((size_t)(NBUCK + 1) * 4);
  int* histM         = (int*)carve((size_t)NCH * NBUCK * 4);
  unsigned int* raw  = (unsigned int*)carve((size_t)E * 4);
  int* rec           = (int*)carve(((size_t)E + 64) * 4);   // +slack for over-read
  __half* h1         = (__half*)carve((size_t)(N + 1) * 64 * 2);  // +zero-row
  __half* g1         = (__half*)carve((size_t)(N + 1) * 64 * 2);
  __half* h2         = (__half*)carve((size_t)(N + 1) * 32 * 2);

  k_histA<<<NCH, 256, 0, stream>>>(edges, E, histM, NBUCK);
  k_colscanA<<<NBUCK, 256, 0, stream>>>(histM, btot, NCH, NBUCK);
  k_bscan<<<1, 256, 0, stream>>>(btot, bbase, rowptr, h1, g1, h2, NBUCK, N, E);
  k_scatter<<<NCH, 256, 0, stream>>>(edges, E, histM, bbase, NBUCK, raw);
  k_sort<<<NBUCK, 256, 0, stream>>>(raw, bbase, rec, rowptr, dinv, N);

  k_gemm<64, 64, false><<<(N + 15) / 16, 256, 0, stream>>>(x, W1, dinv, h1, N);
  k_prop64<<<(N + 3) / 4, 256, 0, stream>>>((const __half2*)h1, rec, rowptr, dinv,
                                            b1, g1, N);
  k_gemm<64, 32, true><<<(N + 31) / 32, 256, 0, stream>>>(g1, W2, dinv, h2, N);
  k_prop32<<<(N + 3) / 4, 256, 0, stream>>>((const __half2*)h2, rec, rowptr, dinv,
                                            b2, (float*)d_out, N);
}